// Round 1
// baseline (470.547 us; speedup 1.0000x reference)
//
#include <hip/hip_runtime.h>
#include <hip/hip_bf16.h>
#include <math.h>

// MoE gate: T=16384 tokens, H=2048, E=160 experts, 8 groups x 20, top-3 groups, top-6 experts.
// Round 1: fp64-accumulated logits (exact ordering vs numpy f64 ref), fused epilogue.

#define T_TOKENS 16384
#define HID      2048
#define NEXP     160
#define NGRP     8
#define EPG      20
#define KGRP     3
#define KTOP     6

#define BT   32      // tokens per block
#define BK   32      // K chunk
#define LSTR 161     // logits LDS stride in doubles (pad to break bank conflicts)

__global__ __launch_bounds__(256, 2)
void moe_gate_main(const float* __restrict__ X, const float* __restrict__ W,
                   float* __restrict__ out, float* __restrict__ piSum,
                   unsigned int* __restrict__ cnt)
{
    // union LDS: staging tiles (xs 4KB + wsh 20KB) then logits (32*161*8 = 41216B)
    __shared__ __align__(16) char smem[BT * LSTR * 8];
    __shared__ double m_arr[BT];
    __shared__ float  invd_arr[BT];

    float*  xs  = (float*)smem;                    // [BK][BT]
    float*  wsh = (float*)(smem + BK * BT * 4);    // [BK][NEXP]
    double* lg  = (double*)smem;                   // [BT][LSTR]

    const int tid = threadIdx.x;
    const int t_i = tid & 15;    // 16 token-threads * 2 tokens = 32
    const int e_i = tid >> 4;    // 16 expert-threads * 10 experts = 160
    const int tokBase = blockIdx.x * BT;

    double acc[2][10];
#pragma unroll
    for (int j = 0; j < 2; ++j)
#pragma unroll
        for (int m = 0; m < 10; ++m) acc[j][m] = 0.0;

    for (int k0 = 0; k0 < HID; k0 += BK) {
        // ---- stage x tile: 32 tokens x 32 k  (transposed to [k][t]) ----
        {
            const int tk = tid >> 3;      // 0..31 token
            const int q  = tid & 7;       // 0..7, 4 floats each
            const float4 xv = *(const float4*)(X + (size_t)(tokBase + tk) * HID + k0 + q * 4);
            float v[4] = {xv.x, xv.y, xv.z, xv.w};
#pragma unroll
            for (int ii = 0; ii < 4; ++ii) xs[(q * 4 + ii) * BT + tk] = v[ii];
        }
        // ---- stage W tile: 160 experts x 32 k (transposed to [k][e]) ----
        for (int i = tid; i < NEXP * 4; i += 256) {
            const int e = i >> 2;         // 0..159
            const int q = i & 3;          // 0..3, 8 floats each
            const float* src = W + (size_t)e * HID + k0 + q * 8;
            const float4 a = *(const float4*)(src);
            const float4 b = *(const float4*)(src + 4);
            float v[8] = {a.x, a.y, a.z, a.w, b.x, b.y, b.z, b.w};
#pragma unroll
            for (int ii = 0; ii < 8; ++ii) wsh[(q * 8 + ii) * NEXP + e] = v[ii];
        }
        __syncthreads();

#pragma unroll 4
        for (int kk = 0; kk < BK; ++kk) {
            const float2 xf = *(const float2*)&xs[kk * BT + t_i * 2];
            const double xd0 = (double)xf.x;
            const double xd1 = (double)xf.y;
            double wd[10];
#pragma unroll
            for (int m2 = 0; m2 < 5; ++m2) {
                const float2 wv = *(const float2*)&wsh[kk * NEXP + e_i * 10 + m2 * 2];
                wd[m2 * 2]     = (double)wv.x;
                wd[m2 * 2 + 1] = (double)wv.y;
            }
#pragma unroll
            for (int m = 0; m < 10; ++m) {
                acc[0][m] = fma(xd0, wd[m], acc[0][m]);
                acc[1][m] = fma(xd1, wd[m], acc[1][m]);
            }
        }
        __syncthreads();
    }

    // ---- dump logits to LDS (tiles dead now) ----
#pragma unroll
    for (int j = 0; j < 2; ++j)
#pragma unroll
        for (int m = 0; m < 10; ++m)
            lg[(t_i * 2 + j) * LSTR + (e_i * 10 + m)] = acc[j][m];
    __syncthreads();

    // ---- phase 1: per-token selection (one thread per token) ----
    if (tid < BT) {
        const int t = tid;
        const double* L = lg + t * LSTR;

        // group maxes
        double g[NGRP];
#pragma unroll
        for (int gi = 0; gi < NGRP; ++gi) {
            double mx = L[gi * EPG];
            for (int j = 1; j < EPG; ++j) {
                const double v = L[gi * EPG + j];
                if (v > mx) mx = v;
            }
            g[gi] = mx;
        }
        // top-3 groups (stable: strict >, first wins)
        int gmask = 0;
#pragma unroll
        for (int p = 0; p < KGRP; ++p) {
            double best = -1.0e300; int bi = 0;
#pragma unroll
            for (int gi = 0; gi < NGRP; ++gi) {
                if (!((gmask >> gi) & 1) && g[gi] > best) { best = g[gi]; bi = gi; }
            }
            gmask |= (1 << bi);
        }
        // softmax stats over all 160 experts
        double mall = g[0];
#pragma unroll
        for (int gi = 1; gi < NGRP; ++gi) if (g[gi] > mall) mall = g[gi];
        float denom = 0.0f;
        for (int e = 0; e < NEXP; ++e)
            denom += expf((float)(L[e] - mall));
        const float invd = 1.0f / denom;
        m_arr[t] = mall;
        invd_arr[t] = invd;

        // top-6 among selected groups (stable argmax passes)
        const int gt = tokBase + t;
        int ch[KTOP];
#pragma unroll
        for (int p = 0; p < KTOP; ++p) {
            double best = -1.0e300; int bi = 0;
            for (int e = 0; e < NEXP; ++e) {
                if (!((gmask >> (e / EPG)) & 1)) continue;
                bool used = false;
#pragma unroll
                for (int j = 0; j < KTOP; ++j)
                    if (j < p && ch[j] == e) used = true;
                const double v = L[e];
                if (!used && v > best) { best = v; bi = e; }
            }
            ch[p] = bi;
            const float wgt = expf((float)(best - mall)) * invd * 16.0f;
            out[(size_t)gt * KTOP + p] = (float)bi;
            out[(size_t)T_TOKENS * KTOP + (size_t)gt * KTOP + p] = wgt;
            atomicAdd(&cnt[bi], 1u);
        }
    }
    __syncthreads();

    // ---- phase 2: per-expert score sums over the block's tokens (for Pi) ----
    if (tid < NEXP) {
        const int e = tid;
        float s = 0.0f;
        for (int t = 0; t < BT; ++t) {
            const double lv = lg[t * LSTR + e];
            s += expf((float)(lv - m_arr[t])) * invd_arr[t];
        }
        atomicAdd(&piSum[e], s);
    }
}

__global__ void moe_gate_aux(const float* __restrict__ piSum,
                             const unsigned int* __restrict__ cnt,
                             float* __restrict__ out)
{
    __shared__ double buf[NEXP];
    const int tid = threadIdx.x;
    if (tid < NEXP) buf[tid] = (double)piSum[tid] * (double)cnt[tid];
    __syncthreads();
    if (tid == 0) {
        double s = 0.0;
        for (int e = 0; e < NEXP; ++e) s += buf[e];
        // aux = 0.001 * sum_e (PiSum/T) * (160 * cnt/(T*K))
        const double aux = s * (0.001 * (double)NEXP) /
                           ((double)T_TOKENS * (double)T_TOKENS * (double)KTOP);
        out[(size_t)T_TOKENS * KTOP * 2] = (float)aux;
    }
}

extern "C" void kernel_launch(void* const* d_in, const int* in_sizes, int n_in,
                              void* d_out, int out_size, void* d_ws, size_t ws_size,
                              hipStream_t stream)
{
    const float* X = (const float*)d_in[0];   // [16384, 2048]
    const float* W = (const float*)d_in[1];   // [160, 2048]
    float* out = (float*)d_out;               // [98304 idx][98304 wgt][1 aux]
    float* piSum = (float*)d_ws;              // [160] f32
    unsigned int* cnt = (unsigned int*)((char*)d_ws + 1024); // [160] u32

    hipMemsetAsync(d_ws, 0, 2048, stream);
    moe_gate_main<<<T_TOKENS / BT, 256, 0, stream>>>(X, W, out, piSum, cnt);
    moe_gate_aux<<<1, 256, 0, stream>>>(piSum, cnt, out);
}

// Round 2
// 246.522 us; speedup vs baseline: 1.9087x; 1.9087x over previous
//
#include <hip/hip_runtime.h>
#include <math.h>

// MoE gate, round 2: split-bf16 MFMA GEMM (hh+hl+lh passes, fp32 acc) with
// zero-LDS main loop (per-wave private K-slices), fused selection epilogue with
// margin flagging, fp64 fixup kernel for ambiguous tokens.

#define T_TOKENS 16384
#define HID      2048
#define NEXP     160
#define NGRP     8
#define EPG      20
#define KGRP     3
#define KTOP     6

#define BT     64      // tokens per block
#define NMT    4       // 16-row M tiles
#define NNT    10      // 16-col N tiles
#define KSLICE 512     // K per wave
#define NSTEPS 16      // K-steps of 32 per wave
#define LSTR   161     // logits LDS stride (floats)

typedef __attribute__((ext_vector_type(8))) short short8;
typedef __attribute__((ext_vector_type(4))) float f32x4;

__device__ __forceinline__ unsigned short f2bf(float f) {
    unsigned u = __float_as_uint(f);
    return (unsigned short)((u + 0x7FFFu + ((u >> 16) & 1u)) >> 16);
}
__device__ __forceinline__ float bf2f(unsigned short s) {
    return __uint_as_float(((unsigned)s) << 16);
}

// ---- pack W into B-fragment order (hi/lo bf16 planes) ------------------------
// B frag for N-tile n, k-step kt (32 k): lane l, elem j <- W[16n+(l&15)][32kt+(l>>4)*8+j]
__global__ __launch_bounds__(256)
void pack_w(const float* __restrict__ W, short* __restrict__ whi, short* __restrict__ wlo)
{
    const int idx = blockIdx.x * 256 + threadIdx.x;   // 160*256 = 40960
    const int e  = idx >> 8;
    const int k0 = (idx & 255) * 8;
    const float* src = W + (size_t)e * HID + k0;
    float x[8];
    *(float4*)&x[0] = *(const float4*)src;
    *(float4*)&x[4] = *(const float4*)(src + 4);
    short8 h, l;
#pragma unroll
    for (int j = 0; j < 8; ++j) {
        unsigned short hb = f2bf(x[j]);
        h[j] = (short)hb;
        l[j] = (short)f2bf(x[j] - bf2f(hb));
    }
    const int kt   = k0 >> 5;
    const int lane = (((k0 >> 3) & 3) << 4) | (e & 15);
    const int n    = e >> 4;
    const size_t addr = ((size_t)(kt * NNT + n)) * 512 + (size_t)lane * 8;
    *(short8*)(whi + addr) = h;
    *(short8*)(wlo + addr) = l;
}

// ---- main: GEMM + fused epilogue --------------------------------------------
__global__ __launch_bounds__(256, 1)
void moe_gate_main(const float* __restrict__ X, const short* __restrict__ whi,
                   const short* __restrict__ wlo, float* __restrict__ out,
                   float* __restrict__ piSum, unsigned int* __restrict__ cnt,
                   unsigned int* __restrict__ flagCnt, unsigned int* __restrict__ flagList)
{
    __shared__ float lgA[BT * LSTR];
    __shared__ float lgB[BT * LSTR];
    __shared__ float m_arr[BT];
    __shared__ float invd_arr[BT];

    const int tid  = threadIdx.x;
    const int wave = tid >> 6;
    const int lane = tid & 63;
    const int lr = lane & 15;      // row/col within tile
    const int lk = lane >> 4;      // k-chunk 0..3
    const int tokBase = blockIdx.x * BT;
    const int kbase = wave * KSLICE;

    f32x4 acc[NMT][NNT];
#pragma unroll
    for (int m = 0; m < NMT; ++m)
#pragma unroll
        for (int n = 0; n < NNT; ++n)
            acc[m][n] = (f32x4){0.f, 0.f, 0.f, 0.f};

    const float* xrow = X + (size_t)(tokBase + lr) * HID + kbase + lk * 8;

    float4 rA[NMT][2], rB[NMT][2];

#define LOADX(buf, ks_) do {                                                    \
    _Pragma("unroll") for (int m = 0; m < NMT; ++m) {                           \
        const float* p_ = xrow + (size_t)m * 16 * HID + (size_t)(ks_) * 32;     \
        buf[m][0] = *(const float4*)p_;                                         \
        buf[m][1] = *(const float4*)(p_ + 4);                                   \
    } } while (0)

#define COMPUTE(buf, ks_) do {                                                  \
    short8 ah_[NMT], al_[NMT];                                                  \
    _Pragma("unroll") for (int m = 0; m < NMT; ++m) {                           \
        float xv_[8];                                                           \
        *(float4*)&xv_[0] = buf[m][0];                                          \
        *(float4*)&xv_[4] = buf[m][1];                                          \
        _Pragma("unroll") for (int j = 0; j < 8; ++j) {                         \
            unsigned short hb_ = f2bf(xv_[j]);                                  \
            ah_[m][j] = (short)hb_;                                             \
            al_[m][j] = (short)f2bf(xv_[j] - bf2f(hb_));                        \
        } }                                                                     \
    const short8* bh_ = (const short8*)whi + (size_t)(wave * 16 + (ks_)) * 640 + lane; \
    const short8* bl_ = (const short8*)wlo + (size_t)(wave * 16 + (ks_)) * 640 + lane; \
    _Pragma("unroll") for (int n = 0; n < NNT; ++n) {                           \
        short8 bhv_ = bh_[n * 64];                                              \
        short8 blv_ = bl_[n * 64];                                              \
        _Pragma("unroll") for (int m = 0; m < NMT; ++m) {                       \
            acc[m][n] = __builtin_amdgcn_mfma_f32_16x16x32_bf16(ah_[m], bhv_, acc[m][n], 0, 0, 0); \
            acc[m][n] = __builtin_amdgcn_mfma_f32_16x16x32_bf16(ah_[m], blv_, acc[m][n], 0, 0, 0); \
            acc[m][n] = __builtin_amdgcn_mfma_f32_16x16x32_bf16(al_[m], bhv_, acc[m][n], 0, 0, 0); \
        } } } while (0)

    LOADX(rA, 0);
#pragma unroll 1
    for (int ks = 0; ks < NSTEPS; ks += 2) {
        LOADX(rB, ks + 1);
        COMPUTE(rA, ks);
        if (ks + 2 < NSTEPS) LOADX(rA, ks + 2);
        COMPUTE(rB, ks + 1);
    }

    // ---- cross-wave reduction: waves 0,1 write lgA/lgB; 2,3 add; then merge ----
    {
        float* dst = (wave & 1) ? lgB : lgA;
        if (wave < 2) {
#pragma unroll
            for (int m = 0; m < NMT; ++m)
#pragma unroll
                for (int n = 0; n < NNT; ++n)
#pragma unroll
                    for (int r = 0; r < 4; ++r)
                        dst[(m * 16 + lk * 4 + r) * LSTR + n * 16 + lr] = acc[m][n][r];
        }
        __syncthreads();
        if (wave >= 2) {
#pragma unroll
            for (int m = 0; m < NMT; ++m)
#pragma unroll
                for (int n = 0; n < NNT; ++n)
#pragma unroll
                    for (int r = 0; r < 4; ++r)
                        dst[(m * 16 + lk * 4 + r) * LSTR + n * 16 + lr] += acc[m][n][r];
        }
        __syncthreads();
        for (int i = tid; i < BT * LSTR; i += 256) lgA[i] += lgB[i];
        __syncthreads();
    }

    // ---- per-token selection (thread = token) ----
    if (tid < BT) {
        const float* L = lgA + tid * LSTR;
        float g[NGRP];
#pragma unroll
        for (int gi = 0; gi < NGRP; ++gi) {
            float mx = L[gi * EPG];
            for (int j = 1; j < EPG; ++j) mx = fmaxf(mx, L[gi * EPG + j]);
            g[gi] = mx;
        }
        int sel[KGRP];
        int gmask = 0;
        float g3 = 0.f;
#pragma unroll
        for (int p = 0; p < KGRP; ++p) {
            float best = -1e30f; int bi = 0;
#pragma unroll
            for (int gi = 0; gi < NGRP; ++gi)
                if (!((gmask >> gi) & 1) && g[gi] > best) { best = g[gi]; bi = gi; }
            sel[p] = bi; gmask |= 1 << bi; g3 = best;
        }
        float g4 = -1e30f;
#pragma unroll
        for (int gi = 0; gi < NGRP; ++gi)
            if (!((gmask >> gi) & 1)) g4 = fmaxf(g4, g[gi]);
        float mall = g[0];
#pragma unroll
        for (int gi = 1; gi < NGRP; ++gi) mall = fmaxf(mall, g[gi]);

        float denom = 0.f;
        for (int e = 0; e < NEXP; ++e) denom += expf(L[e] - mall);
        const float invd = 1.0f / denom;
        m_arr[tid] = mall;
        invd_arr[tid] = invd;

        const int gt = tokBase + tid;
        int ch[7]; float cv[7];
        for (int p = 0; p < 7; ++p) {
            float best = -1e30f; int bi = 0;
#pragma unroll
            for (int s = 0; s < KGRP; ++s) {
                const int base = sel[s] * EPG;
                for (int j = 0; j < EPG; ++j) {
                    const int e = base + j;
                    bool used = false;
#pragma unroll
                    for (int q = 0; q < 7; ++q)
                        if (q < p && ch[q] == e) used = true;
                    const float v = L[e];
                    if (!used && v > best) { best = v; bi = e; }
                }
            }
            ch[p] = bi; cv[p] = best;
            if (p < KTOP) {
                out[(size_t)gt * KTOP + p] = (float)bi;
                out[(size_t)T_TOKENS * KTOP + (size_t)gt * KTOP + p] =
                    expf(best - mall) * invd * 16.0f;
                atomicAdd(&cnt[bi], 1u);
            }
        }
        float mg = g3 - g4;
#pragma unroll
        for (int p = 0; p < KTOP; ++p) mg = fminf(mg, cv[p] - cv[p + 1]);
        if (mg < 1e-4f) {
            const unsigned pos = atomicAdd(flagCnt, 1u);
            flagList[pos] = (unsigned)gt;
        }
    }
    __syncthreads();

    // ---- per-expert Pi partial sums ----
    if (tid < NEXP) {
        float s = 0.f;
        for (int t = 0; t < BT; ++t)
            s += expf(lgA[t * LSTR + tid] - m_arr[t]) * invd_arr[t];
        atomicAdd(&piSum[tid], s);
    }
#undef LOADX
#undef COMPUTE
}

// ---- fp64 fixup for margin-ambiguous tokens ---------------------------------
__global__ __launch_bounds__(256)
void moe_gate_fixup(const float* __restrict__ X, const float* __restrict__ W,
                    float* __restrict__ out, const unsigned int* __restrict__ flagCnt,
                    const unsigned int* __restrict__ flagList)
{
    __shared__ float xs[HID];
    __shared__ double ld[NEXP];
    const int nflag = (int)*flagCnt;
    for (int i = blockIdx.x; i < nflag; i += gridDim.x) {
        const int t = (int)flagList[i];
        __syncthreads();
        for (int k = threadIdx.x; k < HID / 4; k += 256)
            ((float4*)xs)[k] = ((const float4*)(X + (size_t)t * HID))[k];
        __syncthreads();
        if (threadIdx.x < NEXP) {
            const float* wr = W + (size_t)threadIdx.x * HID;
            double a0 = 0.0, a1 = 0.0;
            for (int k = 0; k < HID; k += 8) {
                const float4 wa = *(const float4*)(wr + k);
                const float4 wb = *(const float4*)(wr + k + 4);
                a0 = fma((double)xs[k],     (double)wa.x, a0);
                a1 = fma((double)xs[k + 1], (double)wa.y, a1);
                a0 = fma((double)xs[k + 2], (double)wa.z, a0);
                a1 = fma((double)xs[k + 3], (double)wa.w, a1);
                a0 = fma((double)xs[k + 4], (double)wb.x, a0);
                a1 = fma((double)xs[k + 5], (double)wb.y, a1);
                a0 = fma((double)xs[k + 6], (double)wb.z, a0);
                a1 = fma((double)xs[k + 7], (double)wb.w, a1);
            }
            ld[threadIdx.x] = a0 + a1;
        }
        __syncthreads();
        if (threadIdx.x == 0) {
            double g[NGRP];
#pragma unroll
            for (int gi = 0; gi < NGRP; ++gi) {
                double mx = ld[gi * EPG];
                for (int j = 1; j < EPG; ++j) {
                    const double v = ld[gi * EPG + j];
                    if (v > mx) mx = v;
                }
                g[gi] = mx;
            }
            int gmask = 0;
#pragma unroll
            for (int p = 0; p < KGRP; ++p) {
                double best = -1.0e300; int bi = 0;
#pragma unroll
                for (int gi = 0; gi < NGRP; ++gi)
                    if (!((gmask >> gi) & 1) && g[gi] > best) { best = g[gi]; bi = gi; }
                gmask |= 1 << bi;
            }
            double mall = g[0];
#pragma unroll
            for (int gi = 1; gi < NGRP; ++gi) if (g[gi] > mall) mall = g[gi];
            float denom = 0.f;
            for (int e = 0; e < NEXP; ++e)
                denom += expf((float)(ld[e] - mall));
            const float invd = 1.0f / denom;

            int ch[KTOP];
            for (int p = 0; p < KTOP; ++p) {
                double best = -1.0e300; int bi = 0;
                for (int e = 0; e < NEXP; ++e) {
                    if (!((gmask >> (e / EPG)) & 1)) continue;
                    bool used = false;
#pragma unroll
                    for (int q = 0; q < KTOP; ++q)
                        if (q < p && ch[q] == e) used = true;
                    if (!used && ld[e] > best) { best = ld[e]; bi = e; }
                }
                ch[p] = bi;
                out[(size_t)t * KTOP + p] = (float)bi;
                out[(size_t)T_TOKENS * KTOP + (size_t)t * KTOP + p] =
                    expf((float)(best - mall)) * invd * 16.0f;
            }
        }
        __syncthreads();
    }
}

// ---- aux loss ----------------------------------------------------------------
__global__ void moe_gate_aux(const float* __restrict__ piSum,
                             const unsigned int* __restrict__ cnt,
                             float* __restrict__ out)
{
    __shared__ double buf[NEXP];
    const int tid = threadIdx.x;
    if (tid < NEXP) buf[tid] = (double)piSum[tid] * (double)cnt[tid];
    __syncthreads();
    if (tid == 0) {
        double s = 0.0;
        for (int e = 0; e < NEXP; ++e) s += buf[e];
        const double aux = s * (0.001 * (double)NEXP) /
                           ((double)T_TOKENS * (double)T_TOKENS * (double)KTOP);
        out[(size_t)T_TOKENS * KTOP * 2] = (float)aux;
    }
}

extern "C" void kernel_launch(void* const* d_in, const int* in_sizes, int n_in,
                              void* d_out, int out_size, void* d_ws, size_t ws_size,
                              hipStream_t stream)
{
    const float* X = (const float*)d_in[0];   // [16384, 2048]
    const float* W = (const float*)d_in[1];   // [160, 2048]
    float* out = (float*)d_out;               // [98304 idx][98304 wgt][1 aux]

    char* ws = (char*)d_ws;
    short* whi = (short*)ws;                                  // 655360 B
    short* wlo = (short*)(ws + 655360);                       // 655360 B
    float* piSum = (float*)(ws + 1310720);                    // 640 B
    unsigned int* cnt = (unsigned int*)(ws + 1311360);        // 640 B
    unsigned int* flagCnt = (unsigned int*)(ws + 1312000);    // 16 B
    unsigned int* flagList = (unsigned int*)(ws + 1312016);   // 64 KB

    hipMemsetAsync(ws + 1310720, 0, 1296, stream);
    pack_w<<<160, 256, 0, stream>>>(W, whi, wlo);
    moe_gate_main<<<T_TOKENS / BT, 256, 0, stream>>>(X, whi, wlo, out, piSum, cnt,
                                                     flagCnt, flagList);
    moe_gate_fixup<<<256, 256, 0, stream>>>(X, W, out, flagCnt, flagList);
    moe_gate_aux<<<1, 256, 0, stream>>>(piSum, cnt, out);
}

// Round 3
// 245.063 us; speedup vs baseline: 1.9201x; 1.0060x over previous
//
#include <hip/hip_runtime.h>
#include <math.h>

// MoE gate, round 3: BW-oriented restructure.
// - 8 waves/block, wave = (N-half x K-quarter), no redundant B traffic
// - X staged through LDS: reg-staging, 3 buffers, raw s_barrier + lgkmcnt(0) only
//   (no vmcnt drain in the loop -> global loads stay in flight across barriers)
// - split-bf16 (hi/lo) 3-pass MFMA, fp32 acc; fp64 fixup for margin-ambiguous tokens

#define T_TOKENS 16384
#define HID      2048
#define NEXP     160
#define NGRP     8
#define EPG      20
#define KGRP     3
#define KTOP     6

#define BT   64
#define LSTR 161

typedef __attribute__((ext_vector_type(8))) short short8;
typedef __attribute__((ext_vector_type(4))) float f32x4;
typedef __attribute__((ext_vector_type(4))) unsigned int uint4v;

union U4S8 { uint4v u; short8 s; float4 f; };

__device__ __forceinline__ unsigned short f2bf(float f) {
    unsigned u = __float_as_uint(f);
    return (unsigned short)((u + 0x7FFFu + ((u >> 16) & 1u)) >> 16);
}
__device__ __forceinline__ float bf2f(unsigned short s) {
    return __uint_as_float(((unsigned)s) << 16);
}
__device__ __forceinline__ unsigned cvtpk(float a, float b) {
    unsigned r;
    asm volatile("v_cvt_pk_bf16_f32 %0, %1, %2" : "=v"(r) : "v"(a), "v"(b));
    return r;
}
__device__ __forceinline__ float lo16(unsigned u) { return __uint_as_float(u << 16); }
__device__ __forceinline__ float hi16(unsigned u) { return __uint_as_float(u & 0xFFFF0000u); }

// ---- pack W into B-fragment order, [kq][s][ntile][plane][lane][8] ------------
__global__ __launch_bounds__(256)
void pack_w(const float* __restrict__ W, short* __restrict__ wpk)
{
    const int idx = blockIdx.x * 256 + threadIdx.x;   // 160*256
    const int e  = idx >> 8;
    const int kc = idx & 255;
    const int k0 = kc * 8;
    const float* src = W + (size_t)e * HID + k0;
    float x[8];
    *(float4*)&x[0] = *(const float4*)src;
    *(float4*)&x[4] = *(const float4*)(src + 4);
    short8 h, l;
#pragma unroll
    for (int j = 0; j < 8; ++j) {
        unsigned short hb = f2bf(x[j]);
        h[j] = (short)hb;
        l[j] = (short)f2bf(x[j] - bf2f(hb));
    }
    const int kq   = kc >> 6;
    const int s    = (kc >> 2) & 15;
    const int kg   = kc & 3;
    const int lane = kg * 16 + (e & 15);
    const int nt   = e >> 4;
    const size_t base = (size_t)(((kq * 16 + s) * 10 + nt) * 2) * 1024 + (size_t)lane * 16;
    *(short8*)((char*)wpk + base)        = h;
    *(short8*)((char*)wpk + base + 1024) = l;
}

// ---- main --------------------------------------------------------------------
__global__ __launch_bounds__(512, 2)
void moe_gate_main(const float* __restrict__ X, const short* __restrict__ wpk,
                   float* __restrict__ out, float* __restrict__ piSum,
                   unsigned int* __restrict__ cnt,
                   unsigned int* __restrict__ flagCnt, unsigned int* __restrict__ flagList)
{
    __shared__ __align__(16) char smem[98304];   // 3 x (64 rows x 512B) A-stage; union: logits 64x161 f32
    __shared__ float m_arr[BT];
    __shared__ float invd_arr[BT];

    const int tid  = threadIdx.x;
    const int lane = tid & 63;
    const int wave = tid >> 6;
    const int kq = wave >> 1;
    const int ns = wave & 1;
    const int tokBase = blockIdx.x * BT;

    // staging: thread covers global chunk g=(tid&31) of rows j*16+(tid>>5)
    const float* xp[4];
    {
        const int rsub = tid >> 5;
        const int g = tid & 31;
#pragma unroll
        for (int j = 0; j < 4; ++j)
            xp[j] = X + (size_t)(tokBase + j * 16 + rsub) * HID + (g >> 3) * 512 + (g & 7) * 4;
    }
    const int wbase = (tid >> 5) * 512 + (((tid & 31) ^ ((tid >> 5) & 7)) * 16);
    const int lr = tid & 15;
    const int kg = (tid >> 4) & 3;
    const int rb0 = lr * 512 + (((kq * 8 + kg * 2)     ^ (lr & 7)) * 16);
    const int rb1 = lr * 512 + (((kq * 8 + kg * 2 + 1) ^ (lr & 7)) * 16);
    const char* wb = (const char*)wpk + (size_t)(kq * 16) * 20480 + (ns * 5) * 2048 + lane * 16;

    f32x4 acc[4][5];
#pragma unroll
    for (int m = 0; m < 4; ++m)
#pragma unroll
        for (int n = 0; n < 5; ++n)
            acc[m][n] = (f32x4){0.f, 0.f, 0.f, 0.f};

    float4 xst0[4], xst1[4];
    U4S8 bb0[10], bb1[10];

    // prologue: X(0)->xst0, X(1)->xst1, B(0)->bb0; write X(0) to buf0
#pragma unroll
    for (int j = 0; j < 4; ++j) xst0[j] = *(const float4*)(xp[j]);
#pragma unroll
    for (int j = 0; j < 4; ++j) xst1[j] = *(const float4*)(xp[j] + 32);
#pragma unroll
    for (int i = 0; i < 10; ++i) bb0[i].u = *(const uint4v*)(wb + i * 1024);
#pragma unroll
    for (int j = 0; j < 4; ++j)
        *(float4*)(smem + wbase + j * 8192) = xst0[j];
    asm volatile("s_waitcnt lgkmcnt(0)" ::: "memory");
    __builtin_amdgcn_s_barrier();

#define BODY(S, WSET, LSET, BUSE, BLOAD, DO_WA, DO_LA, DO_LB) {                       \
    if (DO_WA) { _Pragma("unroll") for (int j = 0; j < 4; ++j)                         \
        *(float4*)(smem + (((S) + 1) % 3) * 32768 + wbase + j * 8192) = WSET[j]; }     \
    if (DO_LA) { _Pragma("unroll") for (int j = 0; j < 4; ++j)                         \
        LSET[j] = *(const float4*)(xp[j] + ((S) + 2) * 32); }                          \
    if (DO_LB) { _Pragma("unroll") for (int i = 0; i < 10; ++i)                        \
        BLOAD[i].u = *(const uint4v*)(wb + ((S) + 1) * 20480 + i * 1024); }            \
    _Pragma("unroll") for (int mt = 0; mt < 4; ++mt) {                                 \
        U4S8 a0, a1, ah, al;                                                           \
        a0.f = *(const float4*)(smem + ((S) % 3) * 32768 + mt * 8192 + rb0);           \
        a1.f = *(const float4*)(smem + ((S) % 3) * 32768 + mt * 8192 + rb1);           \
        unsigned ph0 = cvtpk(a0.f.x, a0.f.y), ph1 = cvtpk(a0.f.z, a0.f.w);             \
        unsigned ph2 = cvtpk(a1.f.x, a1.f.y), ph3 = cvtpk(a1.f.z, a1.f.w);             \
        float l0 = a0.f.x - lo16(ph0), l1 = a0.f.y - hi16(ph0);                        \
        float l2 = a0.f.z - lo16(ph1), l3 = a0.f.w - hi16(ph1);                        \
        float l4 = a1.f.x - lo16(ph2), l5 = a1.f.y - hi16(ph2);                        \
        float l6 = a1.f.z - lo16(ph3), l7 = a1.f.w - hi16(ph3);                        \
        unsigned pl0 = cvtpk(l0, l1), pl1 = cvtpk(l2, l3);                             \
        unsigned pl2 = cvtpk(l4, l5), pl3 = cvtpk(l6, l7);                             \
        ah.u[0] = ph0; ah.u[1] = ph1; ah.u[2] = ph2; ah.u[3] = ph3;                    \
        al.u[0] = pl0; al.u[1] = pl1; al.u[2] = pl2; al.u[3] = pl3;                    \
        _Pragma("unroll") for (int nt = 0; nt < 5; ++nt) {                             \
            acc[mt][nt] = __builtin_amdgcn_mfma_f32_16x16x32_bf16(ah.s, BUSE[nt*2].s,   acc[mt][nt], 0, 0, 0); \
            acc[mt][nt] = __builtin_amdgcn_mfma_f32_16x16x32_bf16(ah.s, BUSE[nt*2+1].s, acc[mt][nt], 0, 0, 0); \
            acc[mt][nt] = __builtin_amdgcn_mfma_f32_16x16x32_bf16(al.s, BUSE[nt*2].s,   acc[mt][nt], 0, 0, 0); \
        } }                                                                            \
    asm volatile("s_waitcnt lgkmcnt(0)" ::: "memory");                                 \
    __builtin_amdgcn_s_barrier(); }

    BODY(0,  xst1, xst0, bb0, bb1, 1, 1, 1)
    BODY(1,  xst0, xst1, bb1, bb0, 1, 1, 1)
    BODY(2,  xst1, xst0, bb0, bb1, 1, 1, 1)
    BODY(3,  xst0, xst1, bb1, bb0, 1, 1, 1)
    BODY(4,  xst1, xst0, bb0, bb1, 1, 1, 1)
    BODY(5,  xst0, xst1, bb1, bb0, 1, 1, 1)
    BODY(6,  xst1, xst0, bb0, bb1, 1, 1, 1)
    BODY(7,  xst0, xst1, bb1, bb0, 1, 1, 1)
    BODY(8,  xst1, xst0, bb0, bb1, 1, 1, 1)
    BODY(9,  xst0, xst1, bb1, bb0, 1, 1, 1)
    BODY(10, xst1, xst0, bb0, bb1, 1, 1, 1)
    BODY(11, xst0, xst1, bb1, bb0, 1, 1, 1)
    BODY(12, xst1, xst0, bb0, bb1, 1, 1, 1)
    BODY(13, xst0, xst1, bb1, bb0, 1, 1, 1)
    BODY(14, xst1, xst0, bb0, bb1, 1, 0, 1)
    BODY(15, xst0, xst1, bb1, bb0, 0, 0, 0)
#undef BODY

    // ---- reduce K-quarters into logits LDS ----
    float* lg = (float*)smem;
#pragma unroll
    for (int q = 0; q < 4; ++q) {
        if (kq == q) {
#pragma unroll
            for (int mt = 0; mt < 4; ++mt)
#pragma unroll
            for (int nt = 0; nt < 5; ++nt)
#pragma unroll
            for (int r = 0; r < 4; ++r) {
                const int token  = mt * 16 + (lane >> 4) * 4 + r;
                const int expert = (ns * 5 + nt) * 16 + (lane & 15);
                float* d = &lg[token * LSTR + expert];
                if (q == 0) *d = acc[mt][nt][r]; else *d += acc[mt][nt][r];
            }
        }
        __syncthreads();
    }

    // ---- per-token selection ----
    if (tid < BT) {
        const float* L = lg + tid * LSTR;
        float g[NGRP];
#pragma unroll
        for (int gi = 0; gi < NGRP; ++gi) {
            float mx = L[gi * EPG];
            for (int j = 1; j < EPG; ++j) mx = fmaxf(mx, L[gi * EPG + j]);
            g[gi] = mx;
        }
        int sel[KGRP];
        int gmask = 0;
        float g3 = 0.f;
#pragma unroll
        for (int p = 0; p < KGRP; ++p) {
            float best = -1e30f; int bi = 0;
#pragma unroll
            for (int gi = 0; gi < NGRP; ++gi)
                if (!((gmask >> gi) & 1) && g[gi] > best) { best = g[gi]; bi = gi; }
            sel[p] = bi; gmask |= 1 << bi; g3 = best;
        }
        float g4 = -1e30f;
#pragma unroll
        for (int gi = 0; gi < NGRP; ++gi)
            if (!((gmask >> gi) & 1)) g4 = fmaxf(g4, g[gi]);
        float mall = g[0];
#pragma unroll
        for (int gi = 1; gi < NGRP; ++gi) mall = fmaxf(mall, g[gi]);

        float denom = 0.f;
        for (int e = 0; e < NEXP; ++e) denom += expf(L[e] - mall);
        const float invd = 1.0f / denom;
        m_arr[tid] = mall;
        invd_arr[tid] = invd;

        const int gt = tokBase + tid;
        int ch[7]; float cv[7];
        for (int p = 0; p < 7; ++p) {
            float best = -1e30f; int bi = 0;
#pragma unroll
            for (int s2 = 0; s2 < KGRP; ++s2) {
                const int base = sel[s2] * EPG;
                for (int j = 0; j < EPG; ++j) {
                    const int e = base + j;
                    bool used = false;
#pragma unroll
                    for (int q2 = 0; q2 < 7; ++q2)
                        if (q2 < p && ch[q2] == e) used = true;
                    const float v = L[e];
                    if (!used && v > best) { best = v; bi = e; }
                }
            }
            ch[p] = bi; cv[p] = best;
            if (p < KTOP) {
                out[(size_t)gt * KTOP + p] = (float)bi;
                out[(size_t)T_TOKENS * KTOP + (size_t)gt * KTOP + p] =
                    expf(best - mall) * invd * 16.0f;
                atomicAdd(&cnt[bi], 1u);
            }
        }
        float mg = g3 - g4;
#pragma unroll
        for (int p = 0; p < KTOP; ++p) mg = fminf(mg, cv[p] - cv[p + 1]);
        if (mg < 1e-4f) {
            const unsigned pos = atomicAdd(flagCnt, 1u);
            flagList[pos] = (unsigned)gt;
        }
    }
    __syncthreads();

    // ---- per-expert Pi partial sums ----
    if (tid < NEXP) {
        float s = 0.f;
        for (int t = 0; t < BT; ++t)
            s += expf(lg[t * LSTR + tid] - m_arr[t]) * invd_arr[t];
        atomicAdd(&piSum[tid], s);
    }
}

// ---- fp64 fixup for margin-ambiguous tokens ---------------------------------
__global__ __launch_bounds__(256)
void moe_gate_fixup(const float* __restrict__ X, const float* __restrict__ W,
                    float* __restrict__ out, const unsigned int* __restrict__ flagCnt,
                    const unsigned int* __restrict__ flagList)
{
    __shared__ float xs[HID];
    __shared__ double ld[NEXP];
    const int nflag = (int)*flagCnt;
    for (int i = blockIdx.x; i < nflag; i += gridDim.x) {
        const int t = (int)flagList[i];
        __syncthreads();
        for (int k = threadIdx.x; k < HID / 4; k += 256)
            ((float4*)xs)[k] = ((const float4*)(X + (size_t)t * HID))[k];
        __syncthreads();
        if (threadIdx.x < NEXP) {
            const float* wr = W + (size_t)threadIdx.x * HID;
            double a0 = 0.0, a1 = 0.0;
            for (int k = 0; k < HID; k += 8) {
                const float4 wa = *(const float4*)(wr + k);
                const float4 wb2 = *(const float4*)(wr + k + 4);
                a0 = fma((double)xs[k],     (double)wa.x, a0);
                a1 = fma((double)xs[k + 1], (double)wa.y, a1);
                a0 = fma((double)xs[k + 2], (double)wa.z, a0);
                a1 = fma((double)xs[k + 3], (double)wa.w, a1);
                a0 = fma((double)xs[k + 4], (double)wb2.x, a0);
                a1 = fma((double)xs[k + 5], (double)wb2.y, a1);
                a0 = fma((double)xs[k + 6], (double)wb2.z, a0);
                a1 = fma((double)xs[k + 7], (double)wb2.w, a1);
            }
            ld[threadIdx.x] = a0 + a1;
        }
        __syncthreads();
        if (threadIdx.x == 0) {
            double g[NGRP];
#pragma unroll
            for (int gi = 0; gi < NGRP; ++gi) {
                double mx = ld[gi * EPG];
                for (int j = 1; j < EPG; ++j) {
                    const double v = ld[gi * EPG + j];
                    if (v > mx) mx = v;
                }
                g[gi] = mx;
            }
            int gmask = 0;
#pragma unroll
            for (int p = 0; p < KGRP; ++p) {
                double best = -1.0e300; int bi = 0;
#pragma unroll
                for (int gi = 0; gi < NGRP; ++gi)
                    if (!((gmask >> gi) & 1) && g[gi] > best) { best = g[gi]; bi = gi; }
                gmask |= 1 << bi;
            }
            double mall = g[0];
#pragma unroll
            for (int gi = 1; gi < NGRP; ++gi) if (g[gi] > mall) mall = g[gi];
            float denom = 0.f;
            for (int e = 0; e < NEXP; ++e)
                denom += expf((float)(ld[e] - mall));
            const float invd = 1.0f / denom;

            int ch[KTOP];
            for (int p = 0; p < KTOP; ++p) {
                double best = -1.0e300; int bi = 0;
                for (int e = 0; e < NEXP; ++e) {
                    if (!((gmask >> (e / EPG)) & 1)) continue;
                    bool used = false;
#pragma unroll
                    for (int q = 0; q < KTOP; ++q)
                        if (q < p && ch[q] == e) used = true;
                    if (!used && ld[e] > best) { best = ld[e]; bi = e; }
                }
                ch[p] = bi;
                out[(size_t)t * KTOP + p] = (float)bi;
                out[(size_t)T_TOKENS * KTOP + (size_t)t * KTOP + p] =
                    expf((float)(best - mall)) * invd * 16.0f;
            }
        }
        __syncthreads();
    }
}

// ---- aux loss ----------------------------------------------------------------
__global__ void moe_gate_aux(const float* __restrict__ piSum,
                             const unsigned int* __restrict__ cnt,
                             float* __restrict__ out)
{
    __shared__ double buf[NEXP];
    const int tid = threadIdx.x;
    if (tid < NEXP) buf[tid] = (double)piSum[tid] * (double)cnt[tid];
    __syncthreads();
    if (tid == 0) {
        double s = 0.0;
        for (int e = 0; e < NEXP; ++e) s += buf[e];
        const double aux = s * (0.001 * (double)NEXP) /
                           ((double)T_TOKENS * (double)T_TOKENS * (double)KTOP);
        out[(size_t)T_TOKENS * KTOP * 2] = (float)aux;
    }
}

extern "C" void kernel_launch(void* const* d_in, const int* in_sizes, int n_in,
                              void* d_out, int out_size, void* d_ws, size_t ws_size,
                              hipStream_t stream)
{
    const float* X = (const float*)d_in[0];   // [16384, 2048]
    const float* W = (const float*)d_in[1];   // [160, 2048]
    float* out = (float*)d_out;               // [98304 idx][98304 wgt][1 aux]

    char* ws = (char*)d_ws;
    short* wpk = (short*)ws;                                  // 1,310,720 B
    float* piSum = (float*)(ws + 1310720);                    // 640 B
    unsigned int* cnt = (unsigned int*)(ws + 1311360);        // 640 B
    unsigned int* flagCnt = (unsigned int*)(ws + 1312000);    // 16 B
    unsigned int* flagList = (unsigned int*)(ws + 1312016);   // 64 KB

    hipMemsetAsync(ws + 1310720, 0, 1296, stream);
    pack_w<<<160, 256, 0, stream>>>(W, wpk);
    moe_gate_main<<<T_TOKENS / BT, 512, 0, stream>>>(X, wpk, out, piSum, cnt,
                                                     flagCnt, flagList);
    moe_gate_fixup<<<256, 256, 0, stream>>>(X, W, out, flagCnt, flagList);
    moe_gate_aux<<<1, 256, 0, stream>>>(piSum, cnt, out);
}

// Round 5
// 236.074 us; speedup vs baseline: 1.9932x; 1.0381x over previous
//
#include <hip/hip_runtime.h>
#include <math.h>

// MoE gate, round 5: round-4 structure (global_load_lds staging, counted vmcnt,
// B double-buffered in regs) with the K-space alignment FIX: staged row-slices
// are quarter-interleaved (LDS chunk q*8+j2 <- global K float q*512+S*32+j2*4),
// matching the B-pack layout B(kq,s) <-> K = kq*512+s*32.

#define T_TOKENS 16384
#define HID      2048
#define NEXP     160
#define NGRP     8
#define EPG      20
#define KGRP     3
#define KTOP     6

#define BT   64
#define LSTR 161

typedef __attribute__((ext_vector_type(8))) short short8;
typedef __attribute__((ext_vector_type(4))) float f32x4;
typedef __attribute__((ext_vector_type(4))) unsigned int uint4v;

union U4S8 { uint4v u; short8 s; float4 f; };

__device__ __forceinline__ unsigned short f2bf(float f) {
    unsigned u = __float_as_uint(f);
    return (unsigned short)((u + 0x7FFFu + ((u >> 16) & 1u)) >> 16);
}
__device__ __forceinline__ float bf2f(unsigned short s) {
    return __uint_as_float(((unsigned)s) << 16);
}
__device__ __forceinline__ unsigned cvtpk(float a, float b) {
    unsigned r;
    asm volatile("v_cvt_pk_bf16_f32 %0, %1, %2" : "=v"(r) : "v"(a), "v"(b));
    return r;
}
__device__ __forceinline__ float lo16(unsigned u) { return __uint_as_float(u << 16); }
__device__ __forceinline__ float hi16(unsigned u) { return __uint_as_float(u & 0xFFFF0000u); }

__device__ __forceinline__ void cp16(char* lds, const float* g) {
    __builtin_amdgcn_global_load_lds(
        (const __attribute__((address_space(1))) unsigned int*)g,
        (__attribute__((address_space(3))) unsigned int*)lds, 16, 0, 0);
}

// ---- pack W into B-fragment order, [kq][s][ntile][plane][lane][8] ------------
__global__ __launch_bounds__(256)
void pack_w(const float* __restrict__ W, short* __restrict__ wpk)
{
    const int idx = blockIdx.x * 256 + threadIdx.x;   // 160*256
    const int e  = idx >> 8;
    const int kc = idx & 255;
    const int k0 = kc * 8;
    const float* src = W + (size_t)e * HID + k0;
    float x[8];
    *(float4*)&x[0] = *(const float4*)src;
    *(float4*)&x[4] = *(const float4*)(src + 4);
    short8 h, l;
#pragma unroll
    for (int j = 0; j < 8; ++j) {
        unsigned short hb = f2bf(x[j]);
        h[j] = (short)hb;
        l[j] = (short)f2bf(x[j] - bf2f(hb));
    }
    const int kq   = kc >> 6;
    const int s    = (kc >> 2) & 15;
    const int kg   = kc & 3;
    const int lane = kg * 16 + (e & 15);
    const int nt   = e >> 4;
    const size_t base = (size_t)(((kq * 16 + s) * 10 + nt) * 2) * 1024 + (size_t)lane * 16;
    *(short8*)((char*)wpk + base)        = h;
    *(short8*)((char*)wpk + base + 1024) = l;
}

// ---- main --------------------------------------------------------------------
__global__ __launch_bounds__(512, 2)
void moe_gate_main(const float* __restrict__ X, const short* __restrict__ wpk,
                   float* __restrict__ out, float* __restrict__ piSum,
                   unsigned int* __restrict__ cnt,
                   unsigned int* __restrict__ flagCnt, unsigned int* __restrict__ flagList)
{
    __shared__ __align__(16) char smem[98304];   // 3 x 32KB X buffers; union: logits
    __shared__ float m_arr[BT];
    __shared__ float invd_arr[BT];

    const int tid  = threadIdx.x;
    const int lane = tid & 63;
    const int wave = tid >> 6;
    const int kq = wave >> 1;
    const int ns = wave & 1;
    const int tokBase = blockIdx.x * BT;

    // global_load_lds source pointers.
    // LDS row r = 8*wave + 2*j + (lane>>5); LDS chunk c = lane&31 must hold
    // global chunk g = c ^ (r&7); global decode: quarter q=g>>3, sub j2=g&7,
    // float offset = q*512 + j2*4 (+ S*32 per step).
    const float* xg[4];
#pragma unroll
    for (int j = 0; j < 4; ++j) {
        const int r = 8 * wave + 2 * j + (lane >> 5);
        const int g = (lane & 31) ^ (r & 7);
        xg[j] = X + (size_t)(tokBase + r) * HID + (g >> 3) * 512 + (g & 7) * 4;
    }
    const int lr = lane & 15;
    const int kg = (lane >> 4) & 3;
    const int rb0 = lr * 512 + (((kq * 8 + kg * 2)     ^ (lr & 7)) * 16);
    const int rb1 = lr * 512 + (((kq * 8 + kg * 2 + 1) ^ (lr & 7)) * 16);
    const char* wb = (const char*)wpk + (size_t)(kq * 16) * 20480 + (ns * 5) * 2048
                     + (size_t)lane * 16;

    f32x4 acc[4][5];
#pragma unroll
    for (int m = 0; m < 4; ++m)
#pragma unroll
        for (int n = 0; n < 5; ++n)
            acc[m][n] = (f32x4){0.f, 0.f, 0.f, 0.f};

    U4S8 bbA[10], bbB[10];

    // ---- prologue: B(0)->bbA, X(0)->buf0, X(1)->buf1 ----
#pragma unroll
    for (int i = 0; i < 10; ++i) bbA[i].u = *(const uint4v*)(wb + i * 1024);
#pragma unroll
    for (int j = 0; j < 4; ++j) cp16(smem + wave * 4096 + j * 1024, xg[j]);
#pragma unroll
    for (int j = 0; j < 4; ++j) cp16(smem + 32768 + wave * 4096 + j * 1024, xg[j] + 32);
    asm volatile("s_waitcnt vmcnt(4)" ::: "memory");   // X(0) done; X(1) in flight
    __builtin_amdgcn_s_barrier();
    __builtin_amdgcn_sched_barrier(0);

#define BODY(S, BUSE, BLOAD) {                                                          \
    if ((S) < 15) { _Pragma("unroll") for (int i = 0; i < 10; ++i)                      \
        BLOAD[i].u = *(const uint4v*)(wb + (size_t)((S) + 1) * 20480 + i * 1024); }     \
    if ((S) < 14) { _Pragma("unroll") for (int j = 0; j < 4; ++j)                       \
        cp16(smem + (((S) + 2) % 3) * 32768 + wave * 4096 + j * 1024,                   \
             xg[j] + ((S) + 2) * 32); }                                                 \
    { const char* ab = smem + ((S) % 3) * 32768;                                        \
      _Pragma("unroll") for (int mt = 0; mt < 4; ++mt) {                                \
        U4S8 a0, a1, ah, al;                                                            \
        a0.f = *(const float4*)(ab + mt * 8192 + rb0);                                  \
        a1.f = *(const float4*)(ab + mt * 8192 + rb1);                                  \
        unsigned ph0 = cvtpk(a0.f.x, a0.f.y), ph1 = cvtpk(a0.f.z, a0.f.w);              \
        unsigned ph2 = cvtpk(a1.f.x, a1.f.y), ph3 = cvtpk(a1.f.z, a1.f.w);              \
        float l0 = a0.f.x - lo16(ph0), l1 = a0.f.y - hi16(ph0);                         \
        float l2 = a0.f.z - lo16(ph1), l3 = a0.f.w - hi16(ph1);                         \
        float l4 = a1.f.x - lo16(ph2), l5 = a1.f.y - hi16(ph2);                         \
        float l6 = a1.f.z - lo16(ph3), l7 = a1.f.w - hi16(ph3);                         \
        unsigned pl0 = cvtpk(l0, l1), pl1 = cvtpk(l2, l3);                              \
        unsigned pl2 = cvtpk(l4, l5), pl3 = cvtpk(l6, l7);                              \
        ah.u[0] = ph0; ah.u[1] = ph1; ah.u[2] = ph2; ah.u[3] = ph3;                     \
        al.u[0] = pl0; al.u[1] = pl1; al.u[2] = pl2; al.u[3] = pl3;                     \
        _Pragma("unroll") for (int nt = 0; nt < 5; ++nt) {                              \
            acc[mt][nt] = __builtin_amdgcn_mfma_f32_16x16x32_bf16(ah.s, BUSE[nt*2].s,   acc[mt][nt], 0, 0, 0); \
            acc[mt][nt] = __builtin_amdgcn_mfma_f32_16x16x32_bf16(ah.s, BUSE[nt*2+1].s, acc[mt][nt], 0, 0, 0); \
            acc[mt][nt] = __builtin_amdgcn_mfma_f32_16x16x32_bf16(al.s, BUSE[nt*2].s,   acc[mt][nt], 0, 0, 0); \
        } } }                                                                            \
    if ((S) < 14)      asm volatile("s_waitcnt vmcnt(14) lgkmcnt(0)" ::: "memory");      \
    else if ((S) == 14) asm volatile("s_waitcnt vmcnt(10) lgkmcnt(0)" ::: "memory");     \
    else               asm volatile("s_waitcnt vmcnt(0) lgkmcnt(0)" ::: "memory");       \
    __builtin_amdgcn_s_barrier();                                                        \
    __builtin_amdgcn_sched_barrier(0); }

    BODY(0,  bbA, bbB)
    BODY(1,  bbB, bbA)
    BODY(2,  bbA, bbB)
    BODY(3,  bbB, bbA)
    BODY(4,  bbA, bbB)
    BODY(5,  bbB, bbA)
    BODY(6,  bbA, bbB)
    BODY(7,  bbB, bbA)
    BODY(8,  bbA, bbB)
    BODY(9,  bbB, bbA)
    BODY(10, bbA, bbB)
    BODY(11, bbB, bbA)
    BODY(12, bbA, bbB)
    BODY(13, bbB, bbA)
    BODY(14, bbA, bbB)
    BODY(15, bbB, bbA)
#undef BODY

    // ---- reduce K-quarters into logits LDS ----
    float* lg = (float*)smem;
#pragma unroll
    for (int q = 0; q < 4; ++q) {
        if (kq == q) {
#pragma unroll
            for (int mt = 0; mt < 4; ++mt)
#pragma unroll
            for (int nt = 0; nt < 5; ++nt)
#pragma unroll
            for (int r = 0; r < 4; ++r) {
                const int token  = mt * 16 + (lane >> 4) * 4 + r;
                const int expert = (ns * 5 + nt) * 16 + (lane & 15);
                float* d = &lg[token * LSTR + expert];
                if (q == 0) *d = acc[mt][nt][r]; else *d += acc[mt][nt][r];
            }
        }
        __syncthreads();
    }

    // ---- per-token selection ----
    if (tid < BT) {
        const float* L = lg + tid * LSTR;
        float g[NGRP];
#pragma unroll
        for (int gi = 0; gi < NGRP; ++gi) {
            float mx = L[gi * EPG];
            for (int j = 1; j < EPG; ++j) mx = fmaxf(mx, L[gi * EPG + j]);
            g[gi] = mx;
        }
        int sel[KGRP];
        int gmask = 0;
        float g3 = 0.f;
#pragma unroll
        for (int p = 0; p < KGRP; ++p) {
            float best = -1e30f; int bi = 0;
#pragma unroll
            for (int gi = 0; gi < NGRP; ++gi)
                if (!((gmask >> gi) & 1) && g[gi] > best) { best = g[gi]; bi = gi; }
            sel[p] = bi; gmask |= 1 << bi; g3 = best;
        }
        float g4 = -1e30f;
#pragma unroll
        for (int gi = 0; gi < NGRP; ++gi)
            if (!((gmask >> gi) & 1)) g4 = fmaxf(g4, g[gi]);
        float mall = g[0];
#pragma unroll
        for (int gi = 1; gi < NGRP; ++gi) mall = fmaxf(mall, g[gi]);

        float denom = 0.f;
        for (int e = 0; e < NEXP; ++e) denom += expf(L[e] - mall);
        const float invd = 1.0f / denom;
        m_arr[tid] = mall;
        invd_arr[tid] = invd;

        const int gt = tokBase + tid;
        int ch[7]; float cv[7];
        for (int p = 0; p < 7; ++p) {
            float best = -1e30f; int bi = 0;
#pragma unroll
            for (int s2 = 0; s2 < KGRP; ++s2) {
                const int base = sel[s2] * EPG;
                for (int j = 0; j < EPG; ++j) {
                    const int e = base + j;
                    bool used = false;
#pragma unroll
                    for (int q2 = 0; q2 < 7; ++q2)
                        if (q2 < p && ch[q2] == e) used = true;
                    const float v = L[e];
                    if (!used && v > best) { best = v; bi = e; }
                }
            }
            ch[p] = bi; cv[p] = best;
            if (p < KTOP) {
                out[(size_t)gt * KTOP + p] = (float)bi;
                out[(size_t)T_TOKENS * KTOP + (size_t)gt * KTOP + p] =
                    expf(best - mall) * invd * 16.0f;
                atomicAdd(&cnt[bi], 1u);
            }
        }
        float mg = g3 - g4;
#pragma unroll
        for (int p = 0; p < KTOP; ++p) mg = fminf(mg, cv[p] - cv[p + 1]);
        if (mg < 1e-4f) {
            const unsigned pos = atomicAdd(flagCnt, 1u);
            flagList[pos] = (unsigned)gt;
        }
    }
    __syncthreads();

    // ---- per-expert Pi partial sums ----
    if (tid < NEXP) {
        float s = 0.f;
        for (int t = 0; t < BT; ++t)
            s += expf(lg[t * LSTR + tid] - m_arr[t]) * invd_arr[t];
        atomicAdd(&piSum[tid], s);
    }
}

// ---- fp64 fixup for margin-ambiguous tokens ---------------------------------
__global__ __launch_bounds__(256)
void moe_gate_fixup(const float* __restrict__ X, const float* __restrict__ W,
                    float* __restrict__ out, const unsigned int* __restrict__ flagCnt,
                    const unsigned int* __restrict__ flagList)
{
    __shared__ float xs[HID];
    __shared__ double ld[NEXP];
    const int nflag = (int)*flagCnt;
    for (int i = blockIdx.x; i < nflag; i += gridDim.x) {
        const int t = (int)flagList[i];
        __syncthreads();
        for (int k = threadIdx.x; k < HID / 4; k += 256)
            ((float4*)xs)[k] = ((const float4*)(X + (size_t)t * HID))[k];
        __syncthreads();
        if (threadIdx.x < NEXP) {
            const float* wr = W + (size_t)threadIdx.x * HID;
            double a0 = 0.0, a1 = 0.0;
            for (int k = 0; k < HID; k += 8) {
                const float4 wa = *(const float4*)(wr + k);
                const float4 wb2 = *(const float4*)(wr + k + 4);
                a0 = fma((double)xs[k],     (double)wa.x, a0);
                a1 = fma((double)xs[k + 1], (double)wa.y, a1);
                a0 = fma((double)xs[k + 2], (double)wa.z, a0);
                a1 = fma((double)xs[k + 3], (double)wa.w, a1);
                a0 = fma((double)xs[k + 4], (double)wb2.x, a0);
                a1 = fma((double)xs[k + 5], (double)wb2.y, a1);
                a0 = fma((double)xs[k + 6], (double)wb2.z, a0);
                a1 = fma((double)xs[k + 7], (double)wb2.w, a1);
            }
            ld[threadIdx.x] = a0 + a1;
        }
        __syncthreads();
        if (threadIdx.x == 0) {
            double g[NGRP];
#pragma unroll
            for (int gi = 0; gi < NGRP; ++gi) {
                double mx = ld[gi * EPG];
                for (int j = 1; j < EPG; ++j) {
                    const double v = ld[gi * EPG + j];
                    if (v > mx) mx = v;
                }
                g[gi] = mx;
            }
            int gmask = 0;
#pragma unroll
            for (int p = 0; p < KGRP; ++p) {
                double best = -1.0e300; int bi = 0;
#pragma unroll
                for (int gi = 0; gi < NGRP; ++gi)
                    if (!((gmask >> gi) & 1) && g[gi] > best) { best = g[gi]; bi = gi; }
                gmask |= 1 << bi;
            }
            double mall = g[0];
#pragma unroll
            for (int gi = 1; gi < NGRP; ++gi) if (g[gi] > mall) mall = g[gi];
            float denom = 0.f;
            for (int e = 0; e < NEXP; ++e)
                denom += expf((float)(ld[e] - mall));
            const float invd = 1.0f / denom;

            int ch[KTOP];
            for (int p = 0; p < KTOP; ++p) {
                double best = -1.0e300; int bi = 0;
                for (int e = 0; e < NEXP; ++e) {
                    if (!((gmask >> (e / EPG)) & 1)) continue;
                    bool used = false;
#pragma unroll
                    for (int q = 0; q < KTOP; ++q)
                        if (q < p && ch[q] == e) used = true;
                    if (!used && ld[e] > best) { best = ld[e]; bi = e; }
                }
                ch[p] = bi;
                out[(size_t)t * KTOP + p] = (float)bi;
                out[(size_t)T_TOKENS * KTOP + (size_t)t * KTOP + p] =
                    expf((float)(best - mall)) * invd * 16.0f;
            }
        }
        __syncthreads();
    }
}

// ---- aux loss ----------------------------------------------------------------
__global__ void moe_gate_aux(const float* __restrict__ piSum,
                             const unsigned int* __restrict__ cnt,
                             float* __restrict__ out)
{
    __shared__ double buf[NEXP];
    const int tid = threadIdx.x;
    if (tid < NEXP) buf[tid] = (double)piSum[tid] * (double)cnt[tid];
    __syncthreads();
    if (tid == 0) {
        double s = 0.0;
        for (int e = 0; e < NEXP; ++e) s += buf[e];
        const double aux = s * (0.001 * (double)NEXP) /
                           ((double)T_TOKENS * (double)T_TOKENS * (double)KTOP);
        out[(size_t)T_TOKENS * KTOP * 2] = (float)aux;
    }
}

extern "C" void kernel_launch(void* const* d_in, const int* in_sizes, int n_in,
                              void* d_out, int out_size, void* d_ws, size_t ws_size,
                              hipStream_t stream)
{
    const float* X = (const float*)d_in[0];   // [16384, 2048]
    const float* W = (const float*)d_in[1];   // [160, 2048]
    float* out = (float*)d_out;               // [98304 idx][98304 wgt][1 aux]

    char* ws = (char*)d_ws;
    short* wpk = (short*)ws;                                  // 1,310,720 B
    float* piSum = (float*)(ws + 1310720);                    // 640 B
    unsigned int* cnt = (unsigned int*)(ws + 1311360);        // 640 B
    unsigned int* flagCnt = (unsigned int*)(ws + 1312000);    // 16 B
    unsigned int* flagList = (unsigned int*)(ws + 1312016);   // 64 KB

    hipMemsetAsync(ws + 1310720, 0, 1296, stream);
    pack_w<<<160, 256, 0, stream>>>(W, wpk);
    moe_gate_main<<<T_TOKENS / BT, 512, 0, stream>>>(X, wpk, out, piSum, cnt,
                                                     flagCnt, flagList);
    moe_gate_fixup<<<256, 256, 0, stream>>>(X, W, out, flagCnt, flagList);
    moe_gate_aux<<<1, 256, 0, stream>>>(piSum, cnt, out);
}

// Round 6
// 202.655 us; speedup vs baseline: 2.3219x; 1.1649x over previous
//
#include <hip/hip_runtime.h>
#include <math.h>

// MoE gate, round 6: round-5 GEMM (global_load_lds staging, counted vmcnt,
// B double-buffered in regs) + ATOMIC-FREE epilogue: per-block LDS histogram
// and Pi partials written to workspace; aux kernel reduces them. The ~200us
// invariant across rounds 2/3/5 pointed at global-atomic contention, not GEMM.

#define T_TOKENS 16384
#define HID      2048
#define NEXP     160
#define NGRP     8
#define EPG      20
#define KGRP     3
#define KTOP     6

#define BT     64
#define NBLK   (T_TOKENS / BT)   // 256
#define LSTR   161

typedef __attribute__((ext_vector_type(8))) short short8;
typedef __attribute__((ext_vector_type(4))) float f32x4;
typedef __attribute__((ext_vector_type(4))) unsigned int uint4v;

union U4S8 { uint4v u; short8 s; float4 f; };

__device__ __forceinline__ unsigned short f2bf(float f) {
    unsigned u = __float_as_uint(f);
    return (unsigned short)((u + 0x7FFFu + ((u >> 16) & 1u)) >> 16);
}
__device__ __forceinline__ float bf2f(unsigned short s) {
    return __uint_as_float(((unsigned)s) << 16);
}
__device__ __forceinline__ unsigned cvtpk(float a, float b) {
    unsigned r;
    asm volatile("v_cvt_pk_bf16_f32 %0, %1, %2" : "=v"(r) : "v"(a), "v"(b));
    return r;
}
__device__ __forceinline__ float lo16(unsigned u) { return __uint_as_float(u << 16); }
__device__ __forceinline__ float hi16(unsigned u) { return __uint_as_float(u & 0xFFFF0000u); }

__device__ __forceinline__ void cp16(char* lds, const float* g) {
    __builtin_amdgcn_global_load_lds(
        (const __attribute__((address_space(1))) unsigned int*)g,
        (__attribute__((address_space(3))) unsigned int*)lds, 16, 0, 0);
}

// ---- pack W into B-fragment order, [kq][s][ntile][plane][lane][8] ------------
__global__ __launch_bounds__(256)
void pack_w(const float* __restrict__ W, short* __restrict__ wpk)
{
    const int idx = blockIdx.x * 256 + threadIdx.x;   // 160*256
    const int e  = idx >> 8;
    const int kc = idx & 255;
    const int k0 = kc * 8;
    const float* src = W + (size_t)e * HID + k0;
    float x[8];
    *(float4*)&x[0] = *(const float4*)src;
    *(float4*)&x[4] = *(const float4*)(src + 4);
    short8 h, l;
#pragma unroll
    for (int j = 0; j < 8; ++j) {
        unsigned short hb = f2bf(x[j]);
        h[j] = (short)hb;
        l[j] = (short)f2bf(x[j] - bf2f(hb));
    }
    const int kq   = kc >> 6;
    const int s    = (kc >> 2) & 15;
    const int kg   = kc & 3;
    const int lane = kg * 16 + (e & 15);
    const int nt   = e >> 4;
    const size_t base = (size_t)(((kq * 16 + s) * 10 + nt) * 2) * 1024 + (size_t)lane * 16;
    *(short8*)((char*)wpk + base)        = h;
    *(short8*)((char*)wpk + base + 1024) = l;
}

// ---- main --------------------------------------------------------------------
__global__ __launch_bounds__(512, 2)
void moe_gate_main(const float* __restrict__ X, const short* __restrict__ wpk,
                   float* __restrict__ out, float* __restrict__ piPart,
                   unsigned int* __restrict__ histPart,
                   unsigned int* __restrict__ flagCnt, unsigned int* __restrict__ flagList)
{
    __shared__ __align__(16) char smem[98304];   // 3 x 32KB X buffers; union: logits
    __shared__ float m_arr[BT];
    __shared__ float invd_arr[BT];
    __shared__ unsigned histL[NEXP];

    const int tid  = threadIdx.x;
    const int lane = tid & 63;
    const int wave = tid >> 6;
    const int kq = wave >> 1;
    const int ns = wave & 1;
    const int tokBase = blockIdx.x * BT;

    // global_load_lds source pointers.
    // LDS row r = 8*wave + 2*j + (lane>>5); LDS chunk c = lane&31 holds
    // global chunk g = c ^ (r&7); decode: quarter q=g>>3, sub j2=g&7,
    // float offset = q*512 + j2*4 (+ S*32 per step).
    const float* xg[4];
#pragma unroll
    for (int j = 0; j < 4; ++j) {
        const int r = 8 * wave + 2 * j + (lane >> 5);
        const int g = (lane & 31) ^ (r & 7);
        xg[j] = X + (size_t)(tokBase + r) * HID + (g >> 3) * 512 + (g & 7) * 4;
    }
    const int lr = lane & 15;
    const int kg = (lane >> 4) & 3;
    const int rb0 = lr * 512 + (((kq * 8 + kg * 2)     ^ (lr & 7)) * 16);
    const int rb1 = lr * 512 + (((kq * 8 + kg * 2 + 1) ^ (lr & 7)) * 16);
    const char* wb = (const char*)wpk + (size_t)(kq * 16) * 20480 + (ns * 5) * 2048
                     + (size_t)lane * 16;

    f32x4 acc[4][5];
#pragma unroll
    for (int m = 0; m < 4; ++m)
#pragma unroll
        for (int n = 0; n < 5; ++n)
            acc[m][n] = (f32x4){0.f, 0.f, 0.f, 0.f};

    U4S8 bbA[10], bbB[10];

    // ---- prologue: B(0)->bbA, X(0)->buf0, X(1)->buf1 ----
#pragma unroll
    for (int i = 0; i < 10; ++i) bbA[i].u = *(const uint4v*)(wb + i * 1024);
#pragma unroll
    for (int j = 0; j < 4; ++j) cp16(smem + wave * 4096 + j * 1024, xg[j]);
#pragma unroll
    for (int j = 0; j < 4; ++j) cp16(smem + 32768 + wave * 4096 + j * 1024, xg[j] + 32);
    asm volatile("s_waitcnt vmcnt(4)" ::: "memory");   // X(0) done; X(1) in flight
    __builtin_amdgcn_s_barrier();
    __builtin_amdgcn_sched_barrier(0);

#define BODY(S, BUSE, BLOAD) {                                                          \
    if ((S) < 15) { _Pragma("unroll") for (int i = 0; i < 10; ++i)                      \
        BLOAD[i].u = *(const uint4v*)(wb + (size_t)((S) + 1) * 20480 + i * 1024); }     \
    if ((S) < 14) { _Pragma("unroll") for (int j = 0; j < 4; ++j)                       \
        cp16(smem + (((S) + 2) % 3) * 32768 + wave * 4096 + j * 1024,                   \
             xg[j] + ((S) + 2) * 32); }                                                 \
    { const char* ab = smem + ((S) % 3) * 32768;                                        \
      _Pragma("unroll") for (int mt = 0; mt < 4; ++mt) {                                \
        U4S8 a0, a1, ah, al;                                                            \
        a0.f = *(const float4*)(ab + mt * 8192 + rb0);                                  \
        a1.f = *(const float4*)(ab + mt * 8192 + rb1);                                  \
        unsigned ph0 = cvtpk(a0.f.x, a0.f.y), ph1 = cvtpk(a0.f.z, a0.f.w);              \
        unsigned ph2 = cvtpk(a1.f.x, a1.f.y), ph3 = cvtpk(a1.f.z, a1.f.w);              \
        float l0 = a0.f.x - lo16(ph0), l1 = a0.f.y - hi16(ph0);                         \
        float l2 = a0.f.z - lo16(ph1), l3 = a0.f.w - hi16(ph1);                         \
        float l4 = a1.f.x - lo16(ph2), l5 = a1.f.y - hi16(ph2);                         \
        float l6 = a1.f.z - lo16(ph3), l7 = a1.f.w - hi16(ph3);                         \
        unsigned pl0 = cvtpk(l0, l1), pl1 = cvtpk(l2, l3);                              \
        unsigned pl2 = cvtpk(l4, l5), pl3 = cvtpk(l6, l7);                              \
        ah.u[0] = ph0; ah.u[1] = ph1; ah.u[2] = ph2; ah.u[3] = ph3;                     \
        al.u[0] = pl0; al.u[1] = pl1; al.u[2] = pl2; al.u[3] = pl3;                     \
        _Pragma("unroll") for (int nt = 0; nt < 5; ++nt) {                              \
            acc[mt][nt] = __builtin_amdgcn_mfma_f32_16x16x32_bf16(ah.s, BUSE[nt*2].s,   acc[mt][nt], 0, 0, 0); \
            acc[mt][nt] = __builtin_amdgcn_mfma_f32_16x16x32_bf16(ah.s, BUSE[nt*2+1].s, acc[mt][nt], 0, 0, 0); \
            acc[mt][nt] = __builtin_amdgcn_mfma_f32_16x16x32_bf16(al.s, BUSE[nt*2].s,   acc[mt][nt], 0, 0, 0); \
        } } }                                                                            \
    if ((S) < 14)      asm volatile("s_waitcnt vmcnt(14) lgkmcnt(0)" ::: "memory");      \
    else if ((S) == 14) asm volatile("s_waitcnt vmcnt(10) lgkmcnt(0)" ::: "memory");     \
    else               asm volatile("s_waitcnt vmcnt(0) lgkmcnt(0)" ::: "memory");       \
    __builtin_amdgcn_s_barrier();                                                        \
    __builtin_amdgcn_sched_barrier(0); }

    BODY(0,  bbA, bbB)
    BODY(1,  bbB, bbA)
    BODY(2,  bbA, bbB)
    BODY(3,  bbB, bbA)
    BODY(4,  bbA, bbB)
    BODY(5,  bbB, bbA)
    BODY(6,  bbA, bbB)
    BODY(7,  bbB, bbA)
    BODY(8,  bbA, bbB)
    BODY(9,  bbB, bbA)
    BODY(10, bbA, bbB)
    BODY(11, bbB, bbA)
    BODY(12, bbA, bbB)
    BODY(13, bbB, bbA)
    BODY(14, bbA, bbB)
    BODY(15, bbB, bbA)
#undef BODY

    // ---- reduce K-quarters into logits LDS ----
    float* lg = (float*)smem;
#pragma unroll
    for (int q = 0; q < 4; ++q) {
        if (kq == q) {
#pragma unroll
            for (int mt = 0; mt < 4; ++mt)
#pragma unroll
            for (int nt = 0; nt < 5; ++nt)
#pragma unroll
            for (int r = 0; r < 4; ++r) {
                const int token  = mt * 16 + (lane >> 4) * 4 + r;
                const int expert = (ns * 5 + nt) * 16 + (lane & 15);
                float* d = &lg[token * LSTR + expert];
                if (q == 0) *d = acc[mt][nt][r]; else *d += acc[mt][nt][r];
            }
        }
        __syncthreads();
    }

    if (tid < NEXP) histL[tid] = 0;
    __syncthreads();

    // ---- per-token selection ----
    if (tid < BT) {
        const float* L = lg + tid * LSTR;
        float g[NGRP];
#pragma unroll
        for (int gi = 0; gi < NGRP; ++gi) {
            float mx = L[gi * EPG];
            for (int j = 1; j < EPG; ++j) mx = fmaxf(mx, L[gi * EPG + j]);
            g[gi] = mx;
        }
        int sel[KGRP];
        int gmask = 0;
        float g3 = 0.f;
#pragma unroll
        for (int p = 0; p < KGRP; ++p) {
            float best = -1e30f; int bi = 0;
#pragma unroll
            for (int gi = 0; gi < NGRP; ++gi)
                if (!((gmask >> gi) & 1) && g[gi] > best) { best = g[gi]; bi = gi; }
            sel[p] = bi; gmask |= 1 << bi; g3 = best;
        }
        float g4 = -1e30f;
#pragma unroll
        for (int gi = 0; gi < NGRP; ++gi)
            if (!((gmask >> gi) & 1)) g4 = fmaxf(g4, g[gi]);
        float mall = g[0];
#pragma unroll
        for (int gi = 1; gi < NGRP; ++gi) mall = fmaxf(mall, g[gi]);

        float denom = 0.f;
        for (int e = 0; e < NEXP; ++e) denom += expf(L[e] - mall);
        const float invd = 1.0f / denom;
        m_arr[tid] = mall;
        invd_arr[tid] = invd;

        const int gt = tokBase + tid;
        int ch[7]; float cv[7];
        for (int p = 0; p < 7; ++p) {
            float best = -1e30f; int bi = 0;
#pragma unroll
            for (int s2 = 0; s2 < KGRP; ++s2) {
                const int base = sel[s2] * EPG;
                for (int j = 0; j < EPG; ++j) {
                    const int e = base + j;
                    bool used = false;
#pragma unroll
                    for (int q2 = 0; q2 < 7; ++q2)
                        if (q2 < p && ch[q2] == e) used = true;
                    const float v = L[e];
                    if (!used && v > best) { best = v; bi = e; }
                }
            }
            ch[p] = bi; cv[p] = best;
            if (p < KTOP) {
                out[(size_t)gt * KTOP + p] = (float)bi;
                out[(size_t)T_TOKENS * KTOP + (size_t)gt * KTOP + p] =
                    expf(best - mall) * invd * 16.0f;
                atomicAdd(&histL[bi], 1u);   // LDS atomic, light contention
            }
        }
        float mg = g3 - g4;
#pragma unroll
        for (int p = 0; p < KTOP; ++p) mg = fminf(mg, cv[p] - cv[p + 1]);
        if (mg < 1e-4f) {
            const unsigned pos = atomicAdd(flagCnt, 1u);
            flagList[pos] = (unsigned)gt;
        }
    }
    __syncthreads();

    // ---- per-expert Pi partials + histogram partials (no global atomics) ----
    if (tid < NEXP) {
        float s = 0.f;
        for (int t = 0; t < BT; ++t)
            s += expf(lg[t * LSTR + tid] - m_arr[t]) * invd_arr[t];
        piPart[(size_t)tid * NBLK + blockIdx.x]   = s;
        histPart[(size_t)tid * NBLK + blockIdx.x] = histL[tid];
    }
}

// ---- fp64 fixup for margin-ambiguous tokens ---------------------------------
__global__ __launch_bounds__(256)
void moe_gate_fixup(const float* __restrict__ X, const float* __restrict__ W,
                    float* __restrict__ out, const unsigned int* __restrict__ flagCnt,
                    const unsigned int* __restrict__ flagList)
{
    __shared__ float xs[HID];
    __shared__ double ld[NEXP];
    const int nflag = (int)*flagCnt;
    for (int i = blockIdx.x; i < nflag; i += gridDim.x) {
        const int t = (int)flagList[i];
        __syncthreads();
        for (int k = threadIdx.x; k < HID / 4; k += 256)
            ((float4*)xs)[k] = ((const float4*)(X + (size_t)t * HID))[k];
        __syncthreads();
        if (threadIdx.x < NEXP) {
            const float* wr = W + (size_t)threadIdx.x * HID;
            double a0 = 0.0, a1 = 0.0;
            for (int k = 0; k < HID; k += 8) {
                const float4 wa = *(const float4*)(wr + k);
                const float4 wb2 = *(const float4*)(wr + k + 4);
                a0 = fma((double)xs[k],     (double)wa.x, a0);
                a1 = fma((double)xs[k + 1], (double)wa.y, a1);
                a0 = fma((double)xs[k + 2], (double)wa.z, a0);
                a1 = fma((double)xs[k + 3], (double)wa.w, a1);
                a0 = fma((double)xs[k + 4], (double)wb2.x, a0);
                a1 = fma((double)xs[k + 5], (double)wb2.y, a1);
                a0 = fma((double)xs[k + 6], (double)wb2.z, a0);
                a1 = fma((double)xs[k + 7], (double)wb2.w, a1);
            }
            ld[threadIdx.x] = a0 + a1;
        }
        __syncthreads();
        if (threadIdx.x == 0) {
            double g[NGRP];
#pragma unroll
            for (int gi = 0; gi < NGRP; ++gi) {
                double mx = ld[gi * EPG];
                for (int j = 1; j < EPG; ++j) {
                    const double v = ld[gi * EPG + j];
                    if (v > mx) mx = v;
                }
                g[gi] = mx;
            }
            int gmask = 0;
#pragma unroll
            for (int p = 0; p < KGRP; ++p) {
                double best = -1.0e300; int bi = 0;
#pragma unroll
                for (int gi = 0; gi < NGRP; ++gi)
                    if (!((gmask >> gi) & 1) && g[gi] > best) { best = g[gi]; bi = gi; }
                gmask |= 1 << bi;
            }
            double mall = g[0];
#pragma unroll
            for (int gi = 1; gi < NGRP; ++gi) if (g[gi] > mall) mall = g[gi];
            float denom = 0.f;
            for (int e = 0; e < NEXP; ++e)
                denom += expf((float)(ld[e] - mall));
            const float invd = 1.0f / denom;

            int ch[KTOP];
            for (int p = 0; p < KTOP; ++p) {
                double best = -1.0e300; int bi = 0;
                for (int e = 0; e < NEXP; ++e) {
                    if (!((gmask >> (e / EPG)) & 1)) continue;
                    bool used = false;
#pragma unroll
                    for (int q = 0; q < KTOP; ++q)
                        if (q < p && ch[q] == e) used = true;
                    if (!used && ld[e] > best) { best = ld[e]; bi = e; }
                }
                ch[p] = bi;
                out[(size_t)t * KTOP + p] = (float)bi;
                out[(size_t)T_TOKENS * KTOP + (size_t)t * KTOP + p] =
                    expf((float)(best - mall)) * invd * 16.0f;
            }
        }
        __syncthreads();
    }
}

// ---- aux loss: reduce partials ----------------------------------------------
__global__ __launch_bounds__(256)
void moe_gate_aux(const float* __restrict__ piPart,
                  const unsigned int* __restrict__ histPart,
                  float* __restrict__ out)
{
    __shared__ double buf[NEXP];
    const int tid = threadIdx.x;
    if (tid < NEXP) {
        const float* pp = piPart + (size_t)tid * NBLK;
        const unsigned int* hp = histPart + (size_t)tid * NBLK;
        float s = 0.f;
        unsigned c = 0;
#pragma unroll 8
        for (int b = 0; b < NBLK; ++b) { s += pp[b]; c += hp[b]; }
        buf[tid] = (double)s * (double)c;
    }
    __syncthreads();
    if (tid == 0) {
        double s = 0.0;
        for (int e = 0; e < NEXP; ++e) s += buf[e];
        const double aux = s * (0.001 * (double)NEXP) /
                           ((double)T_TOKENS * (double)T_TOKENS * (double)KTOP);
        out[(size_t)T_TOKENS * KTOP * 2] = (float)aux;
    }
}

extern "C" void kernel_launch(void* const* d_in, const int* in_sizes, int n_in,
                              void* d_out, int out_size, void* d_ws, size_t ws_size,
                              hipStream_t stream)
{
    const float* X = (const float*)d_in[0];   // [16384, 2048]
    const float* W = (const float*)d_in[1];   // [160, 2048]
    float* out = (float*)d_out;               // [98304 idx][98304 wgt][1 aux]

    char* ws = (char*)d_ws;
    short* wpk = (short*)ws;                                    // 1,310,720 B
    float* piPart = (float*)(ws + 1310720);                     // 160*256*4 = 163,840 B
    unsigned int* histPart = (unsigned int*)(ws + 1474560);     // 160*256*4 = 163,840 B
    unsigned int* flagCnt  = (unsigned int*)(ws + 1638400);     // 16 B
    unsigned int* flagList = (unsigned int*)(ws + 1638416);     // 64 KB

    hipMemsetAsync(flagCnt, 0, 16, stream);
    pack_w<<<160, 256, 0, stream>>>(W, wpk);
    moe_gate_main<<<NBLK, 512, 0, stream>>>(X, wpk, out, piPart, histPart,
                                            flagCnt, flagList);
    moe_gate_fixup<<<256, 256, 0, stream>>>(X, W, out, flagCnt, flagList);
    moe_gate_aux<<<1, 256, 0, stream>>>(piPart, histPart, out);
}

// Round 7
// 176.489 us; speedup vs baseline: 2.6662x; 1.1483x over previous
//
#include <hip/hip_runtime.h>
#include <math.h>

// MoE gate, round 7: GEMM identical to round 6 (global_load_lds staging, counted
// vmcnt, B dbuf in regs). NEW wave-parallel epilogue: expert-major logits plane
// (vector LDS reduction), 8-lanes-per-token selection with register candidates
// + shuffle argmax, vectorized Pi phase. Theory: rounds 2/3/5/6's ~175us
// invariant was the serial single-wave epilogue, not the GEMM.

#define T_TOKENS 16384
#define HID      2048
#define NEXP     160
#define NGRP     8
#define EPG      20
#define KGRP     3
#define KTOP     6

#define BT     64
#define NBLK   (T_TOKENS / BT)   // 256
#define LPAD   68                // expert-major row stride in floats (16B aligned)

typedef __attribute__((ext_vector_type(8))) short short8;
typedef __attribute__((ext_vector_type(4))) float f32x4;
typedef __attribute__((ext_vector_type(4))) unsigned int uint4v;

union U4S8 { uint4v u; short8 s; float4 f; };

__device__ __forceinline__ unsigned short f2bf(float f) {
    unsigned u = __float_as_uint(f);
    return (unsigned short)((u + 0x7FFFu + ((u >> 16) & 1u)) >> 16);
}
__device__ __forceinline__ float bf2f(unsigned short s) {
    return __uint_as_float(((unsigned)s) << 16);
}
__device__ __forceinline__ unsigned cvtpk(float a, float b) {
    unsigned r;
    asm volatile("v_cvt_pk_bf16_f32 %0, %1, %2" : "=v"(r) : "v"(a), "v"(b));
    return r;
}
__device__ __forceinline__ float lo16(unsigned u) { return __uint_as_float(u << 16); }
__device__ __forceinline__ float hi16(unsigned u) { return __uint_as_float(u & 0xFFFF0000u); }

__device__ __forceinline__ void cp16(char* lds, const float* g) {
    __builtin_amdgcn_global_load_lds(
        (const __attribute__((address_space(1))) unsigned int*)g,
        (__attribute__((address_space(3))) unsigned int*)lds, 16, 0, 0);
}

// ---- pack W into B-fragment order, [kq][s][ntile][plane][lane][8] ------------
__global__ __launch_bounds__(256)
void pack_w(const float* __restrict__ W, short* __restrict__ wpk)
{
    const int idx = blockIdx.x * 256 + threadIdx.x;   // 160*256
    const int e  = idx >> 8;
    const int kc = idx & 255;
    const int k0 = kc * 8;
    const float* src = W + (size_t)e * HID + k0;
    float x[8];
    *(float4*)&x[0] = *(const float4*)src;
    *(float4*)&x[4] = *(const float4*)(src + 4);
    short8 h, l;
#pragma unroll
    for (int j = 0; j < 8; ++j) {
        unsigned short hb = f2bf(x[j]);
        h[j] = (short)hb;
        l[j] = (short)f2bf(x[j] - bf2f(hb));
    }
    const int kq   = kc >> 6;
    const int s    = (kc >> 2) & 15;
    const int kg   = kc & 3;
    const int lane = kg * 16 + (e & 15);
    const int nt   = e >> 4;
    const size_t base = (size_t)(((kq * 16 + s) * 10 + nt) * 2) * 1024 + (size_t)lane * 16;
    *(short8*)((char*)wpk + base)        = h;
    *(short8*)((char*)wpk + base + 1024) = l;
}

// ---- main --------------------------------------------------------------------
__global__ __launch_bounds__(512, 2)
void moe_gate_main(const float* __restrict__ X, const short* __restrict__ wpk,
                   float* __restrict__ out, float* __restrict__ piPart,
                   unsigned int* __restrict__ histPart,
                   unsigned int* __restrict__ flagCnt, unsigned int* __restrict__ flagList)
{
    __shared__ __align__(16) char smem[98304];   // 3 x 32KB X buffers; union: 2 logit planes
    __shared__ __align__(16) float m_arr[BT];
    __shared__ __align__(16) float invd_arr[BT];
    __shared__ unsigned histL[NEXP];

    const int tid  = threadIdx.x;
    const int lane = tid & 63;
    const int wave = tid >> 6;
    const int kq = wave >> 1;
    const int ns = wave & 1;
    const int tokBase = blockIdx.x * BT;

    const float* xg[4];
#pragma unroll
    for (int j = 0; j < 4; ++j) {
        const int r = 8 * wave + 2 * j + (lane >> 5);
        const int g = (lane & 31) ^ (r & 7);
        xg[j] = X + (size_t)(tokBase + r) * HID + (g >> 3) * 512 + (g & 7) * 4;
    }
    const int lr = lane & 15;
    const int kg = (lane >> 4) & 3;
    const int rb0 = lr * 512 + (((kq * 8 + kg * 2)     ^ (lr & 7)) * 16);
    const int rb1 = lr * 512 + (((kq * 8 + kg * 2 + 1) ^ (lr & 7)) * 16);
    const char* wb = (const char*)wpk + (size_t)(kq * 16) * 20480 + (ns * 5) * 2048
                     + (size_t)lane * 16;

    f32x4 acc[4][5];
#pragma unroll
    for (int m = 0; m < 4; ++m)
#pragma unroll
        for (int n = 0; n < 5; ++n)
            acc[m][n] = (f32x4){0.f, 0.f, 0.f, 0.f};

    U4S8 bbA[10], bbB[10];

    // ---- prologue: B(0)->bbA, X(0)->buf0, X(1)->buf1 ----
#pragma unroll
    for (int i = 0; i < 10; ++i) bbA[i].u = *(const uint4v*)(wb + i * 1024);
#pragma unroll
    for (int j = 0; j < 4; ++j) cp16(smem + wave * 4096 + j * 1024, xg[j]);
#pragma unroll
    for (int j = 0; j < 4; ++j) cp16(smem + 32768 + wave * 4096 + j * 1024, xg[j] + 32);
    asm volatile("s_waitcnt vmcnt(4)" ::: "memory");
    __builtin_amdgcn_s_barrier();
    __builtin_amdgcn_sched_barrier(0);

#define BODY(S, BUSE, BLOAD) {                                                          \
    if ((S) < 15) { _Pragma("unroll") for (int i = 0; i < 10; ++i)                      \
        BLOAD[i].u = *(const uint4v*)(wb + (size_t)((S) + 1) * 20480 + i * 1024); }     \
    if ((S) < 14) { _Pragma("unroll") for (int j = 0; j < 4; ++j)                       \
        cp16(smem + (((S) + 2) % 3) * 32768 + wave * 4096 + j * 1024,                   \
             xg[j] + ((S) + 2) * 32); }                                                 \
    { const char* ab = smem + ((S) % 3) * 32768;                                        \
      _Pragma("unroll") for (int mt = 0; mt < 4; ++mt) {                                \
        U4S8 a0, a1, ah, al;                                                            \
        a0.f = *(const float4*)(ab + mt * 8192 + rb0);                                  \
        a1.f = *(const float4*)(ab + mt * 8192 + rb1);                                  \
        unsigned ph0 = cvtpk(a0.f.x, a0.f.y), ph1 = cvtpk(a0.f.z, a0.f.w);              \
        unsigned ph2 = cvtpk(a1.f.x, a1.f.y), ph3 = cvtpk(a1.f.z, a1.f.w);              \
        float l0 = a0.f.x - lo16(ph0), l1 = a0.f.y - hi16(ph0);                         \
        float l2 = a0.f.z - lo16(ph1), l3 = a0.f.w - hi16(ph1);                         \
        float l4 = a1.f.x - lo16(ph2), l5 = a1.f.y - hi16(ph2);                         \
        float l6 = a1.f.z - lo16(ph3), l7 = a1.f.w - hi16(ph3);                         \
        unsigned pl0 = cvtpk(l0, l1), pl1 = cvtpk(l2, l3);                              \
        unsigned pl2 = cvtpk(l4, l5), pl3 = cvtpk(l6, l7);                              \
        ah.u[0] = ph0; ah.u[1] = ph1; ah.u[2] = ph2; ah.u[3] = ph3;                     \
        al.u[0] = pl0; al.u[1] = pl1; al.u[2] = pl2; al.u[3] = pl3;                     \
        _Pragma("unroll") for (int nt = 0; nt < 5; ++nt) {                              \
            acc[mt][nt] = __builtin_amdgcn_mfma_f32_16x16x32_bf16(ah.s, BUSE[nt*2].s,   acc[mt][nt], 0, 0, 0); \
            acc[mt][nt] = __builtin_amdgcn_mfma_f32_16x16x32_bf16(ah.s, BUSE[nt*2+1].s, acc[mt][nt], 0, 0, 0); \
            acc[mt][nt] = __builtin_amdgcn_mfma_f32_16x16x32_bf16(al.s, BUSE[nt*2].s,   acc[mt][nt], 0, 0, 0); \
        } } }                                                                            \
    if ((S) < 14)      asm volatile("s_waitcnt vmcnt(14) lgkmcnt(0)" ::: "memory");      \
    else if ((S) == 14) asm volatile("s_waitcnt vmcnt(10) lgkmcnt(0)" ::: "memory");     \
    else               asm volatile("s_waitcnt vmcnt(0) lgkmcnt(0)" ::: "memory");       \
    __builtin_amdgcn_s_barrier();                                                        \
    __builtin_amdgcn_sched_barrier(0); }

    BODY(0,  bbA, bbB)
    BODY(1,  bbB, bbA)
    BODY(2,  bbA, bbB)
    BODY(3,  bbB, bbA)
    BODY(4,  bbA, bbB)
    BODY(5,  bbB, bbA)
    BODY(6,  bbA, bbB)
    BODY(7,  bbB, bbA)
    BODY(8,  bbA, bbB)
    BODY(9,  bbB, bbA)
    BODY(10, bbA, bbB)
    BODY(11, bbB, bbA)
    BODY(12, bbA, bbB)
    BODY(13, bbB, bbA)
    BODY(14, bbA, bbB)
    BODY(15, bbB, bbA)
#undef BODY

    // ---- reduce K-quarters into TWO expert-major planes [160][68], then add ----
    float* pA = (float*)smem;
    float* pB = pA + NEXP * LPAD;   // 2*43520B = 87040B <= 98304B

    if ((kq & 1) == 0) {             // kq 0 -> pA, kq 2 -> pB : write
        float* P = (kq == 0) ? pA : pB;
#pragma unroll
        for (int mt = 0; mt < 4; ++mt)
#pragma unroll
        for (int nt = 0; nt < 5; ++nt) {
            const int e = (ns * 5 + nt) * 16 + lr;
            *(f32x4*)&P[e * LPAD + mt * 16 + kg * 4] = acc[mt][nt];
        }
    }
    __syncthreads();
    if (kq & 1) {                    // kq 1 -> pA, kq 3 -> pB : accumulate
        float* P = (kq == 1) ? pA : pB;
#pragma unroll
        for (int mt = 0; mt < 4; ++mt)
#pragma unroll
        for (int nt = 0; nt < 5; ++nt) {
            const int e = (ns * 5 + nt) * 16 + lr;
            f32x4* d = (f32x4*)&P[e * LPAD + mt * 16 + kg * 4];
            *d = *d + acc[mt][nt];
        }
    }
    if (tid < NEXP) histL[tid] = 0;
    __syncthreads();
    for (int i = tid; i < NEXP * LPAD / 4; i += 512) {   // pA += pB (pads carry garbage, never read)
        f32x4* a = (f32x4*)pA + i;
        const f32x4* b = (const f32x4*)pB + i;
        *a = *a + *b;
    }
    __syncthreads();

    // ---- wave-parallel selection: 8 lanes per token ----
    {
        const int t  = tid >> 3;          // token 0..63
        const int gl = tid & 7;           // lane-in-group = expert group id
        const int lbase = lane & 0x38;    // group base lane within wave

        // group max over this lane's 20 experts
        float mg_ = pA[(gl * EPG) * LPAD + t];
#pragma unroll
        for (int j = 1; j < EPG; ++j) mg_ = fmaxf(mg_, pA[(gl * EPG + j) * LPAD + t]);

        float gv[8];
#pragma unroll
        for (int gi = 0; gi < 8; ++gi) gv[gi] = __shfl(mg_, lbase + gi);

        // top-3 groups (strict >, first wins) -- uniform across the 8 lanes
        float best = -1e30f; int bi = 0;
#pragma unroll
        for (int gi = 0; gi < NGRP; ++gi) if (gv[gi] > best) { best = gv[gi]; bi = gi; }
        const int sel0 = bi; int gmask = 1 << bi;
        best = -1e30f; bi = 0;
#pragma unroll
        for (int gi = 0; gi < NGRP; ++gi)
            if (!((gmask >> gi) & 1) && gv[gi] > best) { best = gv[gi]; bi = gi; }
        const int sel1 = bi; gmask |= 1 << bi;
        best = -1e30f; bi = 0;
#pragma unroll
        for (int gi = 0; gi < NGRP; ++gi)
            if (!((gmask >> gi) & 1) && gv[gi] > best) { best = gv[gi]; bi = gi; }
        const int sel2 = bi; gmask |= 1 << bi;
        const float g3v = best;
        float g4v = -1e30f;
#pragma unroll
        for (int gi = 0; gi < NGRP; ++gi)
            if (!((gmask >> gi) & 1)) g4v = fmaxf(g4v, gv[gi]);
        float mall = gv[0];
#pragma unroll
        for (int gi = 1; gi < NGRP; ++gi) mall = fmaxf(mall, gv[gi]);

        // softmax denominator (8-way partial + shuffle tree)
        float dsum = 0.f;
#pragma unroll
        for (int j = 0; j < EPG; ++j)
            dsum += expf(pA[(gl * EPG + j) * LPAD + t] - mall);
        dsum += __shfl_xor(dsum, 1);
        dsum += __shfl_xor(dsum, 2);
        dsum += __shfl_xor(dsum, 4);
        const float invd = 1.0f / dsum;

        // candidates: 60 selected-group experts round-robin over 8 lanes, in regs
        float cvv[8]; int ce[8];
#pragma unroll
        for (int c = 0; c < 8; ++c) {
            const int i = gl + 8 * c;
            if (i < 60) {
                const int sgrp = (i >= 40) ? sel2 : ((i >= 20) ? sel1 : sel0);
                const int e = sgrp * EPG + (i - ((i >= 40) ? 40 : ((i >= 20) ? 20 : 0)));
                ce[c] = e;
                cvv[c] = pA[e * LPAD + t];
            } else { ce[c] = 999; cvv[c] = -1e30f; }
        }

        // 7 argmax passes (value desc, expert-index asc tie-break = lax.top_k order)
        int ch0, ch1, ch2, ch3, ch4, ch5;
        float cv0, cv1, cv2, cv3, cv4, cv5, cv6;
#pragma unroll
        for (int p = 0; p < 7; ++p) {
            float bv = -1e30f; int be = 999;
#pragma unroll
            for (int c = 0; c < 8; ++c)
                if (cvv[c] > bv || (cvv[c] == bv && ce[c] < be)) { bv = cvv[c]; be = ce[c]; }
#pragma unroll
            for (int off = 1; off < 8; off <<= 1) {
                const float ov = __shfl_xor(bv, off);
                const int   oe = __shfl_xor(be, off);
                if (ov > bv || (ov == bv && oe < be)) { bv = ov; be = oe; }
            }
#pragma unroll
            for (int c = 0; c < 8; ++c) if (ce[c] == be) cvv[c] = -1e30f;
            if (p == 0) { ch0 = be; cv0 = bv; }
            else if (p == 1) { ch1 = be; cv1 = bv; }
            else if (p == 2) { ch2 = be; cv2 = bv; }
            else if (p == 3) { ch3 = be; cv3 = bv; }
            else if (p == 4) { ch4 = be; cv4 = bv; }
            else if (p == 5) { ch5 = be; cv5 = bv; }
            else { cv6 = bv; }
        }

        if (gl == 0) {
            const int gt = tokBase + t;
            out[(size_t)gt * KTOP + 0] = (float)ch0;
            out[(size_t)gt * KTOP + 1] = (float)ch1;
            out[(size_t)gt * KTOP + 2] = (float)ch2;
            out[(size_t)gt * KTOP + 3] = (float)ch3;
            out[(size_t)gt * KTOP + 4] = (float)ch4;
            out[(size_t)gt * KTOP + 5] = (float)ch5;
            float* wo = out + (size_t)T_TOKENS * KTOP + (size_t)gt * KTOP;
            wo[0] = expf(cv0 - mall) * invd * 16.0f;
            wo[1] = expf(cv1 - mall) * invd * 16.0f;
            wo[2] = expf(cv2 - mall) * invd * 16.0f;
            wo[3] = expf(cv3 - mall) * invd * 16.0f;
            wo[4] = expf(cv4 - mall) * invd * 16.0f;
            wo[5] = expf(cv5 - mall) * invd * 16.0f;
            atomicAdd(&histL[ch0], 1u); atomicAdd(&histL[ch1], 1u);
            atomicAdd(&histL[ch2], 1u); atomicAdd(&histL[ch3], 1u);
            atomicAdd(&histL[ch4], 1u); atomicAdd(&histL[ch5], 1u);
            m_arr[t] = mall; invd_arr[t] = invd;
            float mg2 = g3v - g4v;
            mg2 = fminf(mg2, cv0 - cv1); mg2 = fminf(mg2, cv1 - cv2);
            mg2 = fminf(mg2, cv2 - cv3); mg2 = fminf(mg2, cv3 - cv4);
            mg2 = fminf(mg2, cv4 - cv5); mg2 = fminf(mg2, cv5 - cv6);
            if (mg2 < 1e-4f) {
                const unsigned pos = atomicAdd(flagCnt, 1u);
                flagList[pos] = (unsigned)(tokBase + t);
            }
        }
    }
    __syncthreads();

    // ---- per-expert Pi partials + histogram partials (vectorized, no atomics) ----
    if (tid < NEXP) {
        const float* Le = pA + tid * LPAD;
        float s = 0.f;
#pragma unroll 4
        for (int t0 = 0; t0 < BT; t0 += 4) {
            const float4 lv = *(const float4*)(Le + t0);
            const float4 mv = *(const float4*)(m_arr + t0);
            const float4 iv = *(const float4*)(invd_arr + t0);
            s += expf(lv.x - mv.x) * iv.x;
            s += expf(lv.y - mv.y) * iv.y;
            s += expf(lv.z - mv.z) * iv.z;
            s += expf(lv.w - mv.w) * iv.w;
        }
        piPart[(size_t)tid * NBLK + blockIdx.x]   = s;
        histPart[(size_t)tid * NBLK + blockIdx.x] = histL[tid];
    }
}

// ---- fp64 fixup for margin-ambiguous tokens ---------------------------------
__global__ __launch_bounds__(256)
void moe_gate_fixup(const float* __restrict__ X, const float* __restrict__ W,
                    float* __restrict__ out, const unsigned int* __restrict__ flagCnt,
                    const unsigned int* __restrict__ flagList)
{
    __shared__ float xs[HID];
    __shared__ double ld[NEXP];
    const int nflag = (int)*flagCnt;
    for (int i = blockIdx.x; i < nflag; i += gridDim.x) {
        const int t = (int)flagList[i];
        __syncthreads();
        for (int k = threadIdx.x; k < HID / 4; k += 256)
            ((float4*)xs)[k] = ((const float4*)(X + (size_t)t * HID))[k];
        __syncthreads();
        if (threadIdx.x < NEXP) {
            const float* wr = W + (size_t)threadIdx.x * HID;
            double a0 = 0.0, a1 = 0.0;
            for (int k = 0; k < HID; k += 8) {
                const float4 wa = *(const float4*)(wr + k);
                const float4 wb2 = *(const float4*)(wr + k + 4);
                a0 = fma((double)xs[k],     (double)wa.x, a0);
                a1 = fma((double)xs[k + 1], (double)wa.y, a1);
                a0 = fma((double)xs[k + 2], (double)wa.z, a0);
                a1 = fma((double)xs[k + 3], (double)wa.w, a1);
                a0 = fma((double)xs[k + 4], (double)wb2.x, a0);
                a1 = fma((double)xs[k + 5], (double)wb2.y, a1);
                a0 = fma((double)xs[k + 6], (double)wb2.z, a0);
                a1 = fma((double)xs[k + 7], (double)wb2.w, a1);
            }
            ld[threadIdx.x] = a0 + a1;
        }
        __syncthreads();
        if (threadIdx.x == 0) {
            double g[NGRP];
#pragma unroll
            for (int gi = 0; gi < NGRP; ++gi) {
                double mx = ld[gi * EPG];
                for (int j = 1; j < EPG; ++j) {
                    const double v = ld[gi * EPG + j];
                    if (v > mx) mx = v;
                }
                g[gi] = mx;
            }
            int gmask = 0;
#pragma unroll
            for (int p = 0; p < KGRP; ++p) {
                double best = -1.0e300; int bi = 0;
#pragma unroll
                for (int gi = 0; gi < NGRP; ++gi)
                    if (!((gmask >> gi) & 1) && g[gi] > best) { best = g[gi]; bi = gi; }
                gmask |= 1 << bi;
            }
            double mall = g[0];
#pragma unroll
            for (int gi = 1; gi < NGRP; ++gi) if (g[gi] > mall) mall = g[gi];
            float denom = 0.f;
            for (int e = 0; e < NEXP; ++e)
                denom += expf((float)(ld[e] - mall));
            const float invd = 1.0f / denom;

            int ch[KTOP];
            for (int p = 0; p < KTOP; ++p) {
                double best = -1.0e300; int bi = 0;
                for (int e = 0; e < NEXP; ++e) {
                    if (!((gmask >> (e / EPG)) & 1)) continue;
                    bool used = false;
#pragma unroll
                    for (int q = 0; q < KTOP; ++q)
                        if (q < p && ch[q] == e) used = true;
                    if (!used && ld[e] > best) { best = ld[e]; bi = e; }
                }
                ch[p] = bi;
                out[(size_t)t * KTOP + p] = (float)bi;
                out[(size_t)T_TOKENS * KTOP + (size_t)t * KTOP + p] =
                    expf((float)(best - mall)) * invd * 16.0f;
            }
        }
        __syncthreads();
    }
}

// ---- aux loss: reduce partials ----------------------------------------------
__global__ __launch_bounds__(256)
void moe_gate_aux(const float* __restrict__ piPart,
                  const unsigned int* __restrict__ histPart,
                  float* __restrict__ out)
{
    __shared__ double buf[NEXP];
    const int tid = threadIdx.x;
    if (tid < NEXP) {
        const float* pp = piPart + (size_t)tid * NBLK;
        const unsigned int* hp = histPart + (size_t)tid * NBLK;
        float s = 0.f;
        unsigned c = 0;
#pragma unroll 8
        for (int b = 0; b < NBLK; ++b) { s += pp[b]; c += hp[b]; }
        buf[tid] = (double)s * (double)c;
    }
    __syncthreads();
    if (tid == 0) {
        double s = 0.0;
        for (int e = 0; e < NEXP; ++e) s += buf[e];
        const double aux = s * (0.001 * (double)NEXP) /
                           ((double)T_TOKENS * (double)T_TOKENS * (double)KTOP);
        out[(size_t)T_TOKENS * KTOP * 2] = (float)aux;
    }
}

extern "C" void kernel_launch(void* const* d_in, const int* in_sizes, int n_in,
                              void* d_out, int out_size, void* d_ws, size_t ws_size,
                              hipStream_t stream)
{
    const float* X = (const float*)d_in[0];   // [16384, 2048]
    const float* W = (const float*)d_in[1];   // [160, 2048]
    float* out = (float*)d_out;               // [98304 idx][98304 wgt][1 aux]

    char* ws = (char*)d_ws;
    short* wpk = (short*)ws;                                    // 1,310,720 B
    float* piPart = (float*)(ws + 1310720);                     // 163,840 B
    unsigned int* histPart = (unsigned int*)(ws + 1474560);     // 163,840 B
    unsigned int* flagCnt  = (unsigned int*)(ws + 1638400);     // 16 B
    unsigned int* flagList = (unsigned int*)(ws + 1638416);     // 64 KB

    hipMemsetAsync(flagCnt, 0, 16, stream);
    pack_w<<<160, 256, 0, stream>>>(W, wpk);
    moe_gate_main<<<NBLK, 512, 0, stream>>>(X, wpk, out, piPart, histPart,
                                            flagCnt, flagList);
    moe_gate_fixup<<<256, 256, 0, stream>>>(X, W, out, flagCnt, flagList);
    moe_gate_aux<<<1, 256, 0, stream>>>(piPart, histPart, out);
}